// Round 1
// 219.346 us; speedup vs baseline: 1.0609x; 1.0609x over previous
//
#include <hip/hip_runtime.h>
#include <math.h>

// Closed-form pipeline with Hermitian (real-output) symmetry:
//   Fx  = fft2_128(x)                 (k1 rows pack-2 real trick, k2 cols)
//   FBh = fft2_256(pad+roll(k)) rows 0..128
//         (k3: row FFT of 25 psf rows; k4: LDS-twiddle-table column DFT)
//   k6 fused: stage FBh rows {p,128-p} in LDS; M=(1-S1)/(S2+b) in regs;
//             FX rows u=p and u=128-p; row IFFT; write Z rows 0..128
//   k7: C2R column IFFT via 128-pt complex FFT fold
// R2: float2 column tiles use width 16 (128 B = bank row) -> conflict-free.
// R3: LDS tiles larger than blockDim need grid-stride loads.
// R4: k4 LDS-issue bound -> registers.
// R5/R6: 150-float2 state spills at the 128-VGPR cap and __launch_bounds__
//   (256,1) does NOT lift it. Fix: factor T[p]=W^{244u}(W^u)^p -> state is
//   S[25]+tw+E (~75 VGPR), recurrence len 25 reseeded exactly per u.
// R7: twiddles T[u][p] are j-invariant -> all 256 threads recomputed the
//   same 825 cmuls + 66 sincos per block (VALUBusy 60%, dep-chain bound).
//   Fix: cooperative 33x25 twiddle table in LDS (broadcast reads), two
//   alternating accumulators; inner loop is 4 independent FMAs per tap.

static __device__ __forceinline__ float2 cmul(float2 a, float2 b) {
    return make_float2(a.x * b.x - a.y * b.y, a.x * b.y + a.y * b.x);
}
static __device__ __forceinline__ float2 cadd(float2 a, float2 b) {
    return make_float2(a.x + b.x, a.y + b.y);
}
static __device__ __forceinline__ float2 csub(float2 a, float2 b) {
    return make_float2(a.x - b.x, a.y - b.y);
}
static __device__ __forceinline__ float2 conjf2(float2 a) {
    return make_float2(a.x, -a.y);
}

// ---------------- Stockham radix-2 FFT in LDS ----------------
template <int N, int R, int SIGN>
static __device__ __forceinline__ int fft_lds_rows(float2 (&buf)[2][R][N]) {
    constexpr int HB = N / 2;
    const int tid = threadIdx.x;
    const int row = tid / HB;
    const int bt = tid % HB;
    int cur = 0, m = 1, sft = 0;
    for (int l = HB; l >= 1; l >>= 1) {
        __syncthreads();
        const int k = bt & (m - 1);
        const int j = bt >> sft;
        float s, c;
        __sincosf((float)SIGN * (float)M_PI * (float)j / (float)l, &s, &c);
        float2 a = buf[cur][row][bt];
        float2 b = buf[cur][row][bt + HB];
        float2 d = make_float2(a.x - b.x, a.y - b.y);
        float2 wd = make_float2(c * d.x - s * d.y, c * d.y + s * d.x);
        const int o = 2 * bt - k;
        buf[cur ^ 1][row][o] = make_float2(a.x + b.x, a.y + b.y);
        buf[cur ^ 1][row][o + m] = wd;
        cur ^= 1;
        m <<= 1;
        sft++;
    }
    __syncthreads();
    return cur;
}

// Column variant: TC columns (TC=16 -> conflict-free), FFT along axis 0.
template <int N, int TC, int SIGN, int THREADS>
static __device__ __forceinline__ int fft_lds_cols(float2 (&buf)[2][N][TC]) {
    constexpr int HB = N / 2;
    constexpr int WORK = HB * TC;
    const int tid = threadIdx.x;
    int cur = 0, m = 1, sft = 0;
    for (int l = HB; l >= 1; l >>= 1) {
        __syncthreads();
        for (int w = tid; w < WORK; w += THREADS) {
            const int col = w % TC;
            const int bt = w / TC;
            const int k = bt & (m - 1);
            const int j = bt >> sft;
            float s, c;
            __sincosf((float)SIGN * (float)M_PI * (float)j / (float)l, &s, &c);
            float2 a = buf[cur][bt][col];
            float2 b = buf[cur][bt + HB][col];
            float2 d = make_float2(a.x - b.x, a.y - b.y);
            float2 wd = make_float2(c * d.x - s * d.y, c * d.y + s * d.x);
            const int o = 2 * bt - k;
            buf[cur ^ 1][o][col] = make_float2(a.x + b.x, a.y + b.y);
            buf[cur ^ 1][o + m][col] = wd;
        }
        cur ^= 1;
        m <<= 1;
        sft++;
    }
    __syncthreads();
    return cur;
}

// K1: row FFT of x (N=128) with pack-2: rows (2r,2r+1) as re+i*im of one FFT.
__global__ __launch_bounds__(256) void k1_fft_rows_x(const float* __restrict__ x,
                                                     float2* __restrict__ Fx) {
    __shared__ float2 buf[2][4][128];
    const int tid = threadIdx.x;
    const int row = tid >> 6;   // pair slot 0..3
    const int t = tid & 63;
    const int gpair = blockIdx.x * 4 + row;  // img*64 + pr
    const float* r0 = x + (size_t)gpair * 256;        // row 2*pr (128 floats)
    const float* r1 = r0 + 128;                       // row 2*pr+1
    const float2 a0 = ((const float2*)r0)[t];
    const float2 a1 = ((const float2*)r1)[t];
    buf[0][row][2 * t].x = a0.x;
    buf[0][row][2 * t].y = a1.x;
    buf[0][row][2 * t + 1].x = a0.y;
    buf[0][row][2 * t + 1].y = a1.y;
    int cur = fft_lds_rows<128, 4, -1>(buf);
    float2* d0 = Fx + (size_t)gpair * 256;            // Fx row 2*pr
    float2* d1 = d0 + 128;
    for (int h = 0; h < 2; ++h) {
        int tt = t + h * 64;
        float2 Zt = buf[cur][row][tt];
        float2 Zm = buf[cur][row][(128 - tt) & 127];
        d0[tt] = make_float2(0.5f * (Zt.x + Zm.x), 0.5f * (Zt.y - Zm.y));
        float ax = Zt.x - Zm.x, ay = Zt.y + Zm.y;
        d1[tt] = make_float2(0.5f * ay, -0.5f * ax);
    }
}

// K2: column FFT of Fx (N=128), in place. 16 cols/block (conflict-free).
__global__ __launch_bounds__(256) void k2_fft_cols_x(float2* __restrict__ Fx) {
    __shared__ float2 buf[2][128][16];
    const int tid = threadIdx.x;
    const int img = blockIdx.x >> 3;
    const int c0 = (blockIdx.x & 7) * 16;
    float2* base = Fx + (size_t)img * 16384 + c0;
    for (int it = 0; it < 8; ++it) {
        int idx = it * 256 + tid;
        buf[0][idx >> 4][idx & 15] = base[(idx >> 4) * 128 + (idx & 15)];
    }
    int cur = fft_lds_cols<128, 16, -1, 256>(buf);
    for (int it = 0; it < 8; ++it) {
        int idx = it * 256 + tid;
        base[(idx >> 4) * 128 + (idx & 15)] = buf[cur][idx >> 4][idx & 15];
    }
}

// K3: row FFT of padded+rolled psf (N=256), compact output [img][25][256].
__global__ __launch_bounds__(128) void k3_fft_rows_k(const float* __restrict__ kin,
                                                     float2* __restrict__ FBtmp) {
    __shared__ float2 buf[2][1][256];
    const int tid = threadIdx.x;  // 128
    const int img = blockIdx.x / 25;
    const int lr = blockIdx.x % 25;
    const float* krow = kin + img * 625 + lr * 25;
    for (int h = 0; h < 2; ++h) {
        int v = tid + h * 128;
        int pc = (v + 12) & 255;
        buf[0][0][v] = make_float2(pc < 25 ? krow[pc] : 0.f, 0.f);
    }
    int cur = fft_lds_rows<256, 1, -1>(buf);
    float2* dst = FBtmp + (size_t)img * 6400 + lr * 256;
    dst[tid] = buf[cur][0][tid];
    dst[tid + 128] = buf[cur][0][tid + 128];
}

// K4: column DFT via cooperative LDS twiddle table (R7).
// FBh[u][j] = sum_p S[p][j] * T[u][p],  T[u][p] = W_256^{u*(p+244)}.
// T is j-invariant: fill the block's 33x25 table once (825 sincos spread
// over 256 threads), then inner loop = broadcast ds_read + 4 indep FMAs.
// Two alternating accumulators halve the accumulate chain depth.
// Row stride padded to 28 float2 (224 B, 16B-aligned) so broadcast reads
// merge into ds_read_b128.
__global__ __launch_bounds__(256) void k4_dft_cols_k(const float2* __restrict__ FBtmp,
                                                     float2* __restrict__ FBh) {
    __shared__ float2 T[33][28];
    const int j = threadIdx.x;
    const int img = blockIdx.x >> 2;
    const int q = blockIdx.x & 3;
    const int ubeg = q * 33;
    const int nu = (ubeg + 33 < 129) ? 33 : (129 - ubeg);
    const float k2pi = -2.f * (float)M_PI / 256.f;

    // Cooperative twiddle-table fill: nu*25 entries, ~4 per thread.
    for (int idx = j; idx < nu * 25; idx += 256) {
        const int ul = idx / 25;
        const int p = idx - ul * 25;
        const int u = ubeg + ul;
        float s, c;
        __sincosf(k2pi * (float)((u * (p + 244)) & 255), &s, &c);
        T[ul][p] = make_float2(c, s);
    }

    const float2* src = FBtmp + (size_t)img * 6400 + j;
    float2 S[25];
#pragma unroll
    for (int p = 0; p < 25; ++p) S[p] = src[p * 256];
    __syncthreads();

    float2* dst = FBh + (size_t)img * 33024 + j;
    for (int ul = 0; ul < nu; ++ul) {
        float2 a0 = make_float2(0.f, 0.f);
        float2 a1 = make_float2(0.f, 0.f);
#pragma unroll
        for (int p = 0; p < 25; ++p) {
            const float2 t = T[ul][p];
            const float2 s = S[p];
            if (p & 1) {
                a1.x = fmaf(t.x, s.x, fmaf(-t.y, s.y, a1.x));
                a1.y = fmaf(t.x, s.y, fmaf(t.y, s.x, a1.y));
            } else {
                a0.x = fmaf(t.x, s.x, fmaf(-t.y, s.y, a0.x));
                a0.y = fmaf(t.x, s.y, fmaf(t.y, s.x, a0.y));
            }
        }
        dst[(size_t)(ubeg + ul) * 256] = make_float2(a0.x + a1.x, a0.y + a1.y);
    }
}

// K6: fused M + FX build + row IFFT, paired rows {p, 128-p} staged in LDS.
// Block = (img, p), p=0..64. Slot row=0 -> u=p, row=1 -> u=128-p.
__global__ __launch_bounds__(256) void k6_fused(const float2* __restrict__ FBh,
                                                const float2* __restrict__ Fx,
                                                const float* __restrict__ alpha,
                                                float2* __restrict__ Z) {
    __shared__ float2 stage[2][256];  // FBh rows p and 128-p
    __shared__ float2 buf[2][2][256];
    const int tid = threadIdx.x;
    const int row = tid >> 7;
    const int t = tid & 127;
    const int img = blockIdx.x / 65;
    const int p = blockIdx.x % 65;
    const int r = p, rp = 128 - p;
    const float2* base = FBh + (size_t)img * 33024;
    stage[0][tid] = base[r * 256 + tid];
    stage[1][tid] = base[rp * 256 + tid];
    __syncthreads();

    const int u = (row == 0) ? p : (128 - p);   // 0..128
    const int um = u & 127;                     // u==128 -> 0
    const int mi = (um == p) ? 0 : 1;           // stage idx holding row um
    const int oi = 1 - mi;                      // stage idx holding row 128-um

    float2 f00 = stage[mi][t];
    float2 f01 = stage[mi][t + 128];
    float2 f10, f11;
    if (um == 0) {  // rows {0,128}: row 128 direct (only p==0)
        f10 = stage[oi][t];
        f11 = stage[oi][t + 128];
    } else {
        f10 = conjf2(stage[oi][(256 - t) & 255]);
        f11 = conjf2(stage[oi][128 - t]);
    }
    float2 fx = Fx[(size_t)img * 16384 + um * 128 + t];

    float si, ci, sj, cj;
    __sincosf(-(float)M_PI * (float)um / 128.f, &si, &ci);
    __sincosf(-(float)M_PI * (float)t / 128.f, &sj, &cj);
    float2 Di0 = make_float2(1.f + ci, si);
    float2 Di1 = make_float2(1.f - ci, -si);
    float2 Dj0 = make_float2(1.f + cj, sj);
    float2 Dj1 = make_float2(1.f - cj, -sj);
    float2 S1 = cadd(cadd(cmul(cmul(f00, Di0), Dj0), cmul(cmul(f10, Di1), Dj0)),
                     cadd(cmul(cmul(f01, Di0), Dj1), cmul(cmul(f11, Di1), Dj1)));
    S1.x *= 0.25f;
    S1.y *= 0.25f;
    float S2 = 0.25f * (f00.x * f00.x + f00.y * f00.y + f01.x * f01.x + f01.y * f01.y +
                        f10.x * f10.x + f10.y * f10.y + f11.x * f11.x + f11.y * f11.y);
    float b = 1.f / (1.f + __expf(9.f - alpha[img & 63])) + 1e-3f;
    float inv = 1.f / (S2 + b);
    float2 mm = make_float2((1.f - S1.x) * inv, (-S1.y) * inv);

    float2 c0v = (u < 128) ? f00 : f10;
    float2 c1v = (u < 128) ? f01 : f11;
    float2 Du = (u < 128) ? make_float2(1.f + ci, si) : make_float2(1.f - ci, -si);
    float2 Dv0 = make_float2(1.f + cj, sj);
    float2 Dv1 = make_float2(1.f - cj, -sj);
    const float scale = 1.f / 65536.f;
    float2 t0 = cadd(cmul(conjf2(c0v), mm), cmul(Du, Dv0));
    float2 t1 = cadd(cmul(conjf2(c1v), mm), cmul(Du, Dv1));
    float2 FX0 = cmul(fx, t0);
    float2 FX1 = cmul(fx, t1);
    buf[0][row][t] = make_float2(FX0.x * scale, FX0.y * scale);
    buf[0][row][t + 128] = make_float2(FX1.x * scale, FX1.y * scale);
    int cur = fft_lds_rows<256, 2, 1>(buf);
    float2* zb = Z + (size_t)img * 33024 + u * 256;  // p=64: both slots u=64, same data
    zb[t] = buf[cur][row][t];
    zb[t + 128] = buf[cur][row][t + 128];
}

// K7: C2R column IFFT, 16 cols/block. Fold rows 0..128 -> 128-pt complex IFFT.
__global__ __launch_bounds__(256) void k7_c2r(const float2* __restrict__ Z,
                                              float* __restrict__ out) {
    __shared__ float2 S[129][16];
    __shared__ float2 buf[2][128][16];
    const int tid = threadIdx.x;
    const int img = blockIdx.x >> 4;
    const int c0 = (blockIdx.x & 15) * 16;
    const float2* zb = Z + (size_t)img * 33024 + c0;
    for (int idx = tid; idx < 129 * 16; idx += 256) {
        int r = idx >> 4, c = idx & 15;
        S[r][c] = zb[r * 256 + c];
    }
    __syncthreads();
    for (int idx = tid; idx < 128 * 16; idx += 256) {
        int u = idx >> 4, c = idx & 15;
        float2 su = S[u][c];
        float2 s2 = conjf2(S[128 - u][c]);
        float2 e = cadd(su, s2);
        float2 o = csub(su, s2);
        float ws_, wc_;
        __sincosf((float)M_PI * (float)u / 128.f, &ws_, &wc_);
        float2 wo = make_float2(wc_ * o.x - ws_ * o.y, wc_ * o.y + ws_ * o.x);
        buf[0][u][c] = make_float2(e.x - wo.y, e.y + wo.x);  // e + i*wo
    }
    int cur = fft_lds_cols<128, 16, 1, 256>(buf);
    float* ob = out + (size_t)img * 65536 + c0;
    for (int idx = tid; idx < 128 * 16; idx += 256) {
        int n = idx >> 4, c = idx & 15;
        float2 y = buf[cur][n][c];
        ob[(2 * n) * 256 + c] = y.x;
        ob[(2 * n + 1) * 256 + c] = y.y;
    }
}

extern "C" void kernel_launch(void* const* d_in, const int* in_sizes, int n_in,
                              void* d_out, int out_size, void* d_ws, size_t ws_size,
                              hipStream_t stream) {
    const float* x = (const float*)d_in[0];      // (4,64,128,128)
    const float* k = (const float*)d_in[1];      // (4,64,25,25)
    const float* alpha = (const float*)d_in[2];  // (1,64,1,1)
    float* out = (float*)d_out;                  // (4,64,256,256)

    float2* Fx = (float2*)d_ws;           // 256*16384   = 32 MB
    float2* FBh = Fx + 256 * 16384;       // 256*129*256 = 67.6 MB
    float2* Z = FBh + 256 * 33024;        // 256*129*256 = 67.6 MB
    float2* FBtmp = Z + 256 * 33024;      // 256*25*256  = 13.1 MB

    hipLaunchKernelGGL(k1_fft_rows_x, dim3(4096), dim3(256), 0, stream, x, Fx);
    hipLaunchKernelGGL(k2_fft_cols_x, dim3(2048), dim3(256), 0, stream, Fx);
    hipLaunchKernelGGL(k3_fft_rows_k, dim3(6400), dim3(128), 0, stream, k, FBtmp);
    hipLaunchKernelGGL(k4_dft_cols_k, dim3(1024), dim3(256), 0, stream, FBtmp, FBh);
    hipLaunchKernelGGL(k6_fused, dim3(256 * 65), dim3(256), 0, stream, FBh, Fx, alpha, Z);
    hipLaunchKernelGGL(k7_c2r, dim3(4096), dim3(256), 0, stream, Z, out);
}

// Round 2
// 204.507 us; speedup vs baseline: 1.1379x; 1.0726x over previous
//
#include <hip/hip_runtime.h>
#include <math.h>

// Closed-form pipeline with Hermitian (real-output) symmetry:
//   Fx  = fft2_128(x)                 (k1 rows pack-2 real trick, k2 cols)
//   FBh = fft2_256(pad+roll(k)) rows 0..128
//         (k3: row FFT of 25 psf rows; k4: LDS-twiddle-table column DFT)
//   k6 fused: stage FBh rows {p,128-p} in LDS; M=(1-S1)/(S2+b) in regs;
//             FX rows u=p and u=128-p; row IFFT; HERMITIAN FOLD in-block;
//             write folded rows Zf[0..127]
//   k7: pure 128-pt C2R column IFFT of Zf
// R2: float2 column tiles use width 16 (128 B = bank row) -> conflict-free.
// R3: LDS tiles larger than blockDim need grid-stride loads.
// R4: k4 LDS-issue bound -> registers.
// R5/R6: 150-float2 state spills at the 128-VGPR cap; factor T -> S[25]+tw+E.
// R7: j-invariant twiddles recomputed per-thread (VALUBusy-bound) ->
//   cooperative LDS twiddle table; k4 51.8 -> gone from top-5.
// R8: k7 was latency-bound (VALUBusy 42%, occ 28%, LDS 49.6 KB):
//   (a) one HB-entry table serves ALL Stockham stages: index bt-(bt&(m-1));
//   (b) fold moved into k6 (block (img,p) already holds the {p,128-p} pair
//       post-IFFT) -> k7 loses S[129][16], the fold pass, and a sync.

static __device__ __forceinline__ float2 cmul(float2 a, float2 b) {
    return make_float2(a.x * b.x - a.y * b.y, a.x * b.y + a.y * b.x);
}
static __device__ __forceinline__ float2 cadd(float2 a, float2 b) {
    return make_float2(a.x + b.x, a.y + b.y);
}
static __device__ __forceinline__ float2 conjf2(float2 a) {
    return make_float2(a.x, -a.y);
}

// Fill tw[i] = (cos(SIGN*pi*i/HB), sin(SIGN*pi*i/HB)) for i in [0,HB).
// No trailing sync: every consumer is separated from the fill by a
// __syncthreads (first stage of the FFT loops, or k6's stage sync).
template <int HB, int SIGN, int THREADS>
static __device__ __forceinline__ void fill_tw(float2* tw) {
    for (int i = threadIdx.x; i < HB; i += THREADS) {
        float s, c;
        __sincosf((float)SIGN * (float)M_PI * (float)i / (float)HB, &s, &c);
        tw[i] = make_float2(c, s);
    }
}

// ---------------- Stockham radix-2 FFT in LDS ----------------
// Twiddle for stage with half-size l, m=HB/l: angle SIGN*pi*(bt>>sft)/l
//   == SIGN*pi*(bt-k)/HB  -> table lookup tw[bt-k], one table for all stages.
template <int N, int R, int SIGN>
static __device__ __forceinline__ int fft_lds_rows(float2 (&buf)[2][R][N],
                                                   const float2* __restrict__ tw) {
    constexpr int HB = N / 2;
    const int tid = threadIdx.x;
    const int row = tid / HB;
    const int bt = tid % HB;
    int cur = 0, m = 1;
    for (int l = HB; l >= 1; l >>= 1) {
        __syncthreads();
        const int k = bt & (m - 1);
        const float2 w = tw[bt - k];
        float2 a = buf[cur][row][bt];
        float2 b = buf[cur][row][bt + HB];
        float2 d = make_float2(a.x - b.x, a.y - b.y);
        float2 wd = make_float2(w.x * d.x - w.y * d.y, w.x * d.y + w.y * d.x);
        const int o = 2 * bt - k;
        buf[cur ^ 1][row][o] = make_float2(a.x + b.x, a.y + b.y);
        buf[cur ^ 1][row][o + m] = wd;
        cur ^= 1;
        m <<= 1;
    }
    __syncthreads();
    return cur;
}

// Column variant: TC columns (TC=16 -> conflict-free), FFT along axis 0.
template <int N, int TC, int SIGN, int THREADS>
static __device__ __forceinline__ int fft_lds_cols(float2 (&buf)[2][N][TC],
                                                   const float2* __restrict__ tw) {
    constexpr int HB = N / 2;
    constexpr int WORK = HB * TC;
    const int tid = threadIdx.x;
    int cur = 0, m = 1;
    for (int l = HB; l >= 1; l >>= 1) {
        __syncthreads();
        for (int w0 = tid; w0 < WORK; w0 += THREADS) {
            const int col = w0 % TC;
            const int bt = w0 / TC;
            const int k = bt & (m - 1);
            const float2 w = tw[bt - k];
            float2 a = buf[cur][bt][col];
            float2 b = buf[cur][bt + HB][col];
            float2 d = make_float2(a.x - b.x, a.y - b.y);
            float2 wd = make_float2(w.x * d.x - w.y * d.y, w.x * d.y + w.y * d.x);
            const int o = 2 * bt - k;
            buf[cur ^ 1][o][col] = make_float2(a.x + b.x, a.y + b.y);
            buf[cur ^ 1][o + m][col] = wd;
        }
        cur ^= 1;
        m <<= 1;
    }
    __syncthreads();
    return cur;
}

// K1: row FFT of x (N=128) with pack-2: rows (2r,2r+1) as re+i*im of one FFT.
__global__ __launch_bounds__(256) void k1_fft_rows_x(const float* __restrict__ x,
                                                     float2* __restrict__ Fx) {
    __shared__ float2 buf[2][4][128];
    __shared__ float2 tw64m[64];
    const int tid = threadIdx.x;
    const int row = tid >> 6;   // pair slot 0..3
    const int t = tid & 63;
    fill_tw<64, -1, 256>(tw64m);
    const int gpair = blockIdx.x * 4 + row;  // img*64 + pr
    const float* r0 = x + (size_t)gpair * 256;        // row 2*pr (128 floats)
    const float* r1 = r0 + 128;                       // row 2*pr+1
    const float2 a0 = ((const float2*)r0)[t];
    const float2 a1 = ((const float2*)r1)[t];
    buf[0][row][2 * t].x = a0.x;
    buf[0][row][2 * t].y = a1.x;
    buf[0][row][2 * t + 1].x = a0.y;
    buf[0][row][2 * t + 1].y = a1.y;
    int cur = fft_lds_rows<128, 4, -1>(buf, tw64m);
    float2* d0 = Fx + (size_t)gpair * 256;            // Fx row 2*pr
    float2* d1 = d0 + 128;
    for (int h = 0; h < 2; ++h) {
        int tt = t + h * 64;
        float2 Zt = buf[cur][row][tt];
        float2 Zm = buf[cur][row][(128 - tt) & 127];
        d0[tt] = make_float2(0.5f * (Zt.x + Zm.x), 0.5f * (Zt.y - Zm.y));
        float ax = Zt.x - Zm.x, ay = Zt.y + Zm.y;
        d1[tt] = make_float2(0.5f * ay, -0.5f * ax);
    }
}

// K2: column FFT of Fx (N=128), in place. 16 cols/block (conflict-free).
__global__ __launch_bounds__(256) void k2_fft_cols_x(float2* __restrict__ Fx) {
    __shared__ float2 buf[2][128][16];
    __shared__ float2 tw64m[64];
    const int tid = threadIdx.x;
    const int img = blockIdx.x >> 3;
    const int c0 = (blockIdx.x & 7) * 16;
    fill_tw<64, -1, 256>(tw64m);
    float2* base = Fx + (size_t)img * 16384 + c0;
    for (int it = 0; it < 8; ++it) {
        int idx = it * 256 + tid;
        buf[0][idx >> 4][idx & 15] = base[(idx >> 4) * 128 + (idx & 15)];
    }
    int cur = fft_lds_cols<128, 16, -1, 256>(buf, tw64m);
    for (int it = 0; it < 8; ++it) {
        int idx = it * 256 + tid;
        base[(idx >> 4) * 128 + (idx & 15)] = buf[cur][idx >> 4][idx & 15];
    }
}

// K3: row FFT of padded+rolled psf (N=256), compact output [img][25][256].
__global__ __launch_bounds__(128) void k3_fft_rows_k(const float* __restrict__ kin,
                                                     float2* __restrict__ FBtmp) {
    __shared__ float2 buf[2][1][256];
    __shared__ float2 tw128m[128];
    const int tid = threadIdx.x;  // 128
    const int img = blockIdx.x / 25;
    const int lr = blockIdx.x % 25;
    fill_tw<128, -1, 128>(tw128m);
    const float* krow = kin + img * 625 + lr * 25;
    for (int h = 0; h < 2; ++h) {
        int v = tid + h * 128;
        int pc = (v + 12) & 255;
        buf[0][0][v] = make_float2(pc < 25 ? krow[pc] : 0.f, 0.f);
    }
    int cur = fft_lds_rows<256, 1, -1>(buf, tw128m);
    float2* dst = FBtmp + (size_t)img * 6400 + lr * 256;
    dst[tid] = buf[cur][0][tid];
    dst[tid + 128] = buf[cur][0][tid + 128];
}

// K4: column DFT via cooperative LDS twiddle table (R7).
__global__ __launch_bounds__(256) void k4_dft_cols_k(const float2* __restrict__ FBtmp,
                                                     float2* __restrict__ FBh) {
    __shared__ float2 T[33][28];
    const int j = threadIdx.x;
    const int img = blockIdx.x >> 2;
    const int q = blockIdx.x & 3;
    const int ubeg = q * 33;
    const int nu = (ubeg + 33 < 129) ? 33 : (129 - ubeg);
    const float k2pi = -2.f * (float)M_PI / 256.f;

    for (int idx = j; idx < nu * 25; idx += 256) {
        const int ul = idx / 25;
        const int p = idx - ul * 25;
        const int u = ubeg + ul;
        float s, c;
        __sincosf(k2pi * (float)((u * (p + 244)) & 255), &s, &c);
        T[ul][p] = make_float2(c, s);
    }

    const float2* src = FBtmp + (size_t)img * 6400 + j;
    float2 S[25];
#pragma unroll
    for (int p = 0; p < 25; ++p) S[p] = src[p * 256];
    __syncthreads();

    float2* dst = FBh + (size_t)img * 33024 + j;
    for (int ul = 0; ul < nu; ++ul) {
        float2 a0 = make_float2(0.f, 0.f);
        float2 a1 = make_float2(0.f, 0.f);
#pragma unroll
        for (int p = 0; p < 25; ++p) {
            const float2 t = T[ul][p];
            const float2 s = S[p];
            if (p & 1) {
                a1.x = fmaf(t.x, s.x, fmaf(-t.y, s.y, a1.x));
                a1.y = fmaf(t.x, s.y, fmaf(t.y, s.x, a1.y));
            } else {
                a0.x = fmaf(t.x, s.x, fmaf(-t.y, s.y, a0.x));
                a0.y = fmaf(t.x, s.y, fmaf(t.y, s.x, a0.y));
            }
        }
        dst[(size_t)(ubeg + ul) * 256] = make_float2(a0.x + a1.x, a0.y + a1.y);
    }
}

// K6: fused M + FX build + row IFFT + Hermitian column fold.
// Block = (img, p), p=0..64. Slot row=0 -> u=p, row=1 -> u=128-p.
// After the row IFFT, buf holds spatial-row pair {Z[p], Z[128-p]} -- exactly
// the fold pair. Emit folded rows Zf[u] = e + i*w.o (w = e^{+i pi u/128}):
//   row0 covers u=0..64, row1 covers u=65..127 (p=1..63); p=0 row1 (u=128)
//   and p=64 row1 (dup of u=64) skip the write.
__global__ __launch_bounds__(256) void k6_fused(const float2* __restrict__ FBh,
                                                const float2* __restrict__ Fx,
                                                const float* __restrict__ alpha,
                                                float2* __restrict__ Zf) {
    __shared__ float2 stage[2][256];  // FBh rows p and 128-p
    __shared__ float2 buf[2][2][256];
    __shared__ float2 twp[128];       // e^{+i pi k/128}: IFFT + D-factors + fold
    const int tid = threadIdx.x;
    const int row = tid >> 7;
    const int t = tid & 127;
    const int img = blockIdx.x / 65;
    const int p = blockIdx.x % 65;
    fill_tw<128, 1, 256>(twp);
    const int r = p, rp = 128 - p;
    const float2* base = FBh + (size_t)img * 33024;
    stage[0][tid] = base[r * 256 + tid];
    stage[1][tid] = base[rp * 256 + tid];
    __syncthreads();

    const int u = (row == 0) ? p : (128 - p);   // 0..128
    const int um = u & 127;                     // u==128 -> 0
    const int mi = (um == p) ? 0 : 1;           // stage idx holding row um
    const int oi = 1 - mi;                      // stage idx holding row 128-um

    float2 f00 = stage[mi][t];
    float2 f01 = stage[mi][t + 128];
    float2 f10, f11;
    if (um == 0) {  // rows {0,128}: row 128 direct (only p==0)
        f10 = stage[oi][t];
        f11 = stage[oi][t + 128];
    } else {
        f10 = conjf2(stage[oi][(256 - t) & 255]);
        f11 = conjf2(stage[oi][128 - t]);
    }
    float2 fx = Fx[(size_t)img * 16384 + um * 128 + t];

    // (ci,si) = cos/sin(-pi*um/128) = conj of twp[um]; same for (cj,sj) at t.
    const float ci = twp[um].x, si = -twp[um].y;
    const float cj = twp[t].x, sj = -twp[t].y;
    float2 Di0 = make_float2(1.f + ci, si);
    float2 Di1 = make_float2(1.f - ci, -si);
    float2 Dj0 = make_float2(1.f + cj, sj);
    float2 Dj1 = make_float2(1.f - cj, -sj);
    float2 S1 = cadd(cadd(cmul(cmul(f00, Di0), Dj0), cmul(cmul(f10, Di1), Dj0)),
                     cadd(cmul(cmul(f01, Di0), Dj1), cmul(cmul(f11, Di1), Dj1)));
    S1.x *= 0.25f;
    S1.y *= 0.25f;
    float S2 = 0.25f * (f00.x * f00.x + f00.y * f00.y + f01.x * f01.x + f01.y * f01.y +
                        f10.x * f10.x + f10.y * f10.y + f11.x * f11.x + f11.y * f11.y);
    float b = 1.f / (1.f + __expf(9.f - alpha[img & 63])) + 1e-3f;
    float inv = 1.f / (S2 + b);
    float2 mm = make_float2((1.f - S1.x) * inv, (-S1.y) * inv);

    float2 c0v = (u < 128) ? f00 : f10;
    float2 c1v = (u < 128) ? f01 : f11;
    float2 Du = (u < 128) ? make_float2(1.f + ci, si) : make_float2(1.f - ci, -si);
    float2 Dv0 = make_float2(1.f + cj, sj);
    float2 Dv1 = make_float2(1.f - cj, -sj);
    const float scale = 1.f / 65536.f;
    float2 t0 = cadd(cmul(conjf2(c0v), mm), cmul(Du, Dv0));
    float2 t1 = cadd(cmul(conjf2(c1v), mm), cmul(Du, Dv1));
    float2 FX0 = cmul(fx, t0);
    float2 FX1 = cmul(fx, t1);
    buf[0][row][t] = make_float2(FX0.x * scale, FX0.y * scale);
    buf[0][row][t + 128] = make_float2(FX1.x * scale, FX1.y * scale);
    int cur = fft_lds_rows<256, 2, 1>(buf, twp);

    // Hermitian fold: Zf[u0] = (Z[u0]+conj(Z[128-u0])) + i*w.(Z[u0]-conj(Z[128-u0]))
    const int u0 = u;  // row0: p (<=64); row1: 128-p
    const bool dowrite = (row == 0) || (p > 0 && p < 64);
    if (dowrite) {
        const float2 w = twp[u0];  // u0 <= 127 whenever dowrite
        float2* zb = Zf + (size_t)img * 32768 + (size_t)u0 * 256;
        for (int h = 0; h < 2; ++h) {
            int jj = t + h * 128;
            float2 su = buf[cur][row][jj];
            float2 s2 = buf[cur][row ^ 1][jj];
            float2 e = make_float2(su.x + s2.x, su.y - s2.y);   // su + conj(s2)
            float2 o = make_float2(su.x - s2.x, su.y + s2.y);   // su - conj(s2)
            float2 wo = make_float2(w.x * o.x - w.y * o.y, w.x * o.y + w.y * o.x);
            zb[jj] = make_float2(e.x - wo.y, e.y + wo.x);       // e + i*wo
        }
    }
}

// K7: pure C2R column IFFT, 16 cols/block, fold already done in k6.
__global__ __launch_bounds__(256) void k7_c2r(const float2* __restrict__ Zf,
                                              float* __restrict__ out) {
    __shared__ float2 buf[2][128][16];
    __shared__ float2 tw64p[64];  // e^{+i pi k/64}
    const int tid = threadIdx.x;
    const int img = blockIdx.x >> 4;
    const int c0 = (blockIdx.x & 15) * 16;
    fill_tw<64, 1, 256>(tw64p);
    const float2* zb = Zf + (size_t)img * 32768 + c0;
    for (int it = 0; it < 8; ++it) {
        int idx = it * 256 + tid;
        buf[0][idx >> 4][idx & 15] = zb[(idx >> 4) * 256 + (idx & 15)];
    }
    int cur = fft_lds_cols<128, 16, 1, 256>(buf, tw64p);
    float* ob = out + (size_t)img * 65536 + c0;
    for (int it = 0; it < 8; ++it) {
        int idx = it * 256 + tid;
        int n = idx >> 4, c = idx & 15;
        float2 y = buf[cur][n][c];
        ob[(2 * n) * 256 + c] = y.x;
        ob[(2 * n + 1) * 256 + c] = y.y;
    }
}

extern "C" void kernel_launch(void* const* d_in, const int* in_sizes, int n_in,
                              void* d_out, int out_size, void* d_ws, size_t ws_size,
                              hipStream_t stream) {
    const float* x = (const float*)d_in[0];      // (4,64,128,128)
    const float* k = (const float*)d_in[1];      // (4,64,25,25)
    const float* alpha = (const float*)d_in[2];  // (1,64,1,1)
    float* out = (float*)d_out;                  // (4,64,256,256)

    float2* Fx = (float2*)d_ws;           // 256*16384   = 32 MB
    float2* FBh = Fx + 256 * 16384;       // 256*129*256 = 67.6 MB
    float2* Zf = FBh + 256 * 33024;       // 256*128*256 = 64 MB (folded)
    float2* FBtmp = Zf + 256 * 32768;     // 256*25*256  = 13.1 MB

    hipLaunchKernelGGL(k1_fft_rows_x, dim3(4096), dim3(256), 0, stream, x, Fx);
    hipLaunchKernelGGL(k2_fft_cols_x, dim3(2048), dim3(256), 0, stream, Fx);
    hipLaunchKernelGGL(k3_fft_rows_k, dim3(6400), dim3(128), 0, stream, k, FBtmp);
    hipLaunchKernelGGL(k4_dft_cols_k, dim3(1024), dim3(256), 0, stream, FBtmp, FBh);
    hipLaunchKernelGGL(k6_fused, dim3(256 * 65), dim3(256), 0, stream, FBh, Fx, alpha, Zf);
    hipLaunchKernelGGL(k7_c2r, dim3(4096), dim3(256), 0, stream, Zf, out);
}

// Round 3
// 194.221 us; speedup vs baseline: 1.1982x; 1.0530x over previous
//
#include <hip/hip_runtime.h>
#include <math.h>

// Closed-form pipeline with Hermitian (real-output) symmetry:
//   Fx  = fft2_128(x)                 (k1 rows pack-2 real trick, k2 cols)
//   FBh = fft2_256(pad+roll(k)) rows 0..128
//         (k3: row FFT of 25 psf rows; k4: LDS-twiddle-table column DFT)
//   k6 fused: stage 4 FBh rows {pa,128-pa,pb,128-pb}; M=(1-S1)/(S2+b);
//             FX rows; radix-4 row IFFT (wave-local, barrier-free);
//             Hermitian fold in-block; write Zf[0..127]
//   k7: pure 128-pt C2R column IFFT of Zf (radix-4)
// R7: j-invariant twiddles -> cooperative LDS twiddle tables everywhere.
// R8: single HB-table serves all Stockham stages (index bt-(bt&(m-1)));
//     fold moved into k6.
// R9: k6 was VALU+barrier bound (VALUBusy 65%, 2.13M bank-conflict cycles):
//   (a) radix-4 Stockham (Y[4jm+tm+k] = w^{jt}*DFT4, w-table 192 entries);
//   (b) wave-owns-row: 4 row slots x 64 lanes -> FFT stages are wave-local
//       (in-order DS within a wave) -> NO barriers in the FFT loop (9->2);
//   (c) pad phi(i)=i+(i>>3) -> radix-4 scatter writes ~2-way (free).
//   k2/k7 cols keep barriers (rows mix across waves) but go radix-4 (8->5).

static __device__ __forceinline__ float2 cmul(float2 a, float2 b) {
    return make_float2(a.x * b.x - a.y * b.y, a.x * b.y + a.y * b.x);
}
static __device__ __forceinline__ float2 cadd(float2 a, float2 b) {
    return make_float2(a.x + b.x, a.y + b.y);
}
static __device__ __forceinline__ float2 csub(float2 a, float2 b) {
    return make_float2(a.x - b.x, a.y - b.y);
}
static __device__ __forceinline__ float2 conjf2(float2 a) {
    return make_float2(a.x, -a.y);
}
static __device__ __forceinline__ int PHI(int i) { return i + (i >> 3); }

// Fill tw[i] = (cos(SIGN*pi*i/HB), sin(SIGN*pi*i/HB)) for i in [0,HB).
template <int HB, int SIGN, int THREADS>
static __device__ __forceinline__ void fill_tw(float2* tw) {
    for (int i = threadIdx.x; i < HB; i += THREADS) {
        float s, c;
        __sincosf((float)SIGN * (float)M_PI * (float)i / (float)HB, &s, &c);
        tw[i] = make_float2(c, s);
    }
}

// ---------------- radix-2 Stockham rows (k1/k3) ----------------
template <int N, int R, int SIGN>
static __device__ __forceinline__ int fft_lds_rows(float2 (&buf)[2][R][N],
                                                   const float2* __restrict__ tw) {
    constexpr int HB = N / 2;
    const int tid = threadIdx.x;
    const int row = tid / HB;
    const int bt = tid % HB;
    int cur = 0, m = 1;
    for (int l = HB; l >= 1; l >>= 1) {
        __syncthreads();
        const int k = bt & (m - 1);
        const float2 w = tw[bt - k];
        float2 a = buf[cur][row][bt];
        float2 b = buf[cur][row][bt + HB];
        float2 d = make_float2(a.x - b.x, a.y - b.y);
        float2 wd = make_float2(w.x * d.x - w.y * d.y, w.x * d.y + w.y * d.x);
        const int o = 2 * bt - k;
        buf[cur ^ 1][row][o] = make_float2(a.x + b.x, a.y + b.y);
        buf[cur ^ 1][row][o + m] = wd;
        cur ^= 1;
        m <<= 1;
    }
    __syncthreads();
    return cur;
}

// ---------------- mixed radix-4/2 Stockham, 128-pt columns ----------------
// tw[i] = e^{SIGN*2*pi*i*i/128}... i.e. angle SIGN*pi*i/64, need i < 96.
// Stages: 3x radix-4 ((L,m)=(32,1),(8,4),(2,16)) + twiddle-free radix-2 tail.
template <int SIGN, int THREADS>
static __device__ __forceinline__ int fft4_cols_128(float2 (&buf)[2][128][16],
                                                    const float2* __restrict__ tw) {
    const int tid = threadIdx.x;
    int cur = 0, m = 1;
#pragma unroll
    for (int st = 0; st < 3; ++st) {
        __syncthreads();
        for (int w0 = tid; w0 < 512; w0 += THREADS) {
            const int col = w0 & 15;
            const int bq = w0 >> 4;
            const int k = bq & (m - 1);
            const int jm = bq - k;
            const float2 w1 = tw[jm];
            const float2 w2 = tw[2 * jm];
            const float2 w3 = tw[3 * jm];
            float2 a0 = buf[cur][bq][col];
            float2 a1 = buf[cur][bq + 32][col];
            float2 a2 = buf[cur][bq + 64][col];
            float2 a3 = buf[cur][bq + 96][col];
            float2 s02 = cadd(a0, a2), d02 = csub(a0, a2);
            float2 s13 = cadd(a1, a3), d13 = csub(a1, a3);
            float2 b0 = cadd(s02, s13), b2 = csub(s02, s13);
            float2 b1 = make_float2(d02.x - (float)SIGN * d13.y,
                                    d02.y + (float)SIGN * d13.x);
            float2 b3 = make_float2(d02.x + (float)SIGN * d13.y,
                                    d02.y - (float)SIGN * d13.x);
            const int o = 4 * jm + k;
            buf[cur ^ 1][o][col] = b0;
            buf[cur ^ 1][o + m][col] = cmul(w1, b1);
            buf[cur ^ 1][o + 2 * m][col] = cmul(w2, b2);
            buf[cur ^ 1][o + 3 * m][col] = cmul(w3, b3);
        }
        cur ^= 1;
        m <<= 2;
    }
    __syncthreads();
    for (int w0 = tid; w0 < 1024; w0 += THREADS) {  // radix-2 tail, m=64, j=0
        const int col = w0 & 15;
        const int bt = w0 >> 4;
        float2 a = buf[cur][bt][col];
        float2 b = buf[cur][bt + 64][col];
        buf[cur ^ 1][bt][col] = cadd(a, b);
        buf[cur ^ 1][bt + 64][col] = csub(a, b);
    }
    cur ^= 1;
    __syncthreads();
    return cur;
}

// K1: row FFT of x (N=128) with pack-2: rows (2r,2r+1) as re+i*im of one FFT.
__global__ __launch_bounds__(256) void k1_fft_rows_x(const float* __restrict__ x,
                                                     float2* __restrict__ Fx) {
    __shared__ float2 buf[2][4][128];
    __shared__ float2 tw64m[64];
    const int tid = threadIdx.x;
    const int row = tid >> 6;   // pair slot 0..3
    const int t = tid & 63;
    fill_tw<64, -1, 256>(tw64m);
    const int gpair = blockIdx.x * 4 + row;  // img*64 + pr
    const float* r0 = x + (size_t)gpair * 256;        // row 2*pr (128 floats)
    const float* r1 = r0 + 128;                       // row 2*pr+1
    const float2 a0 = ((const float2*)r0)[t];
    const float2 a1 = ((const float2*)r1)[t];
    buf[0][row][2 * t].x = a0.x;
    buf[0][row][2 * t].y = a1.x;
    buf[0][row][2 * t + 1].x = a0.y;
    buf[0][row][2 * t + 1].y = a1.y;
    int cur = fft_lds_rows<128, 4, -1>(buf, tw64m);
    float2* d0 = Fx + (size_t)gpair * 256;            // Fx row 2*pr
    float2* d1 = d0 + 128;
    for (int h = 0; h < 2; ++h) {
        int tt = t + h * 64;
        float2 Zt = buf[cur][row][tt];
        float2 Zm = buf[cur][row][(128 - tt) & 127];
        d0[tt] = make_float2(0.5f * (Zt.x + Zm.x), 0.5f * (Zt.y - Zm.y));
        float ax = Zt.x - Zm.x, ay = Zt.y + Zm.y;
        d1[tt] = make_float2(0.5f * ay, -0.5f * ax);
    }
}

// K2: column FFT of Fx (N=128), in place. 16 cols/block, radix-4.
__global__ __launch_bounds__(256) void k2_fft_cols_x(float2* __restrict__ Fx) {
    __shared__ float2 buf[2][128][16];
    __shared__ float2 tw[96];
    const int tid = threadIdx.x;
    const int img = blockIdx.x >> 3;
    const int c0 = (blockIdx.x & 7) * 16;
    for (int i = tid; i < 96; i += 256) {
        float s, c;
        __sincosf(-(float)M_PI * (float)i / 64.f, &s, &c);
        tw[i] = make_float2(c, s);
    }
    float2* base = Fx + (size_t)img * 16384 + c0;
    for (int it = 0; it < 8; ++it) {
        int idx = it * 256 + tid;
        buf[0][idx >> 4][idx & 15] = base[(idx >> 4) * 128 + (idx & 15)];
    }
    int cur = fft4_cols_128<-1, 256>(buf, tw);
    for (int it = 0; it < 8; ++it) {
        int idx = it * 256 + tid;
        base[(idx >> 4) * 128 + (idx & 15)] = buf[cur][idx >> 4][idx & 15];
    }
}

// K3: row FFT of padded+rolled psf (N=256), compact output [img][25][256].
__global__ __launch_bounds__(128) void k3_fft_rows_k(const float* __restrict__ kin,
                                                     float2* __restrict__ FBtmp) {
    __shared__ float2 buf[2][1][256];
    __shared__ float2 tw128m[128];
    const int tid = threadIdx.x;  // 128
    const int img = blockIdx.x / 25;
    const int lr = blockIdx.x % 25;
    fill_tw<128, -1, 128>(tw128m);
    const float* krow = kin + img * 625 + lr * 25;
    for (int h = 0; h < 2; ++h) {
        int v = tid + h * 128;
        int pc = (v + 12) & 255;
        buf[0][0][v] = make_float2(pc < 25 ? krow[pc] : 0.f, 0.f);
    }
    int cur = fft_lds_rows<256, 1, -1>(buf, tw128m);
    float2* dst = FBtmp + (size_t)img * 6400 + lr * 256;
    dst[tid] = buf[cur][0][tid];
    dst[tid + 128] = buf[cur][0][tid + 128];
}

// K4: column DFT via cooperative LDS twiddle table (R7).
__global__ __launch_bounds__(256) void k4_dft_cols_k(const float2* __restrict__ FBtmp,
                                                     float2* __restrict__ FBh) {
    __shared__ float2 T[33][28];
    const int j = threadIdx.x;
    const int img = blockIdx.x >> 2;
    const int q = blockIdx.x & 3;
    const int ubeg = q * 33;
    const int nu = (ubeg + 33 < 129) ? 33 : (129 - ubeg);
    const float k2pi = -2.f * (float)M_PI / 256.f;

    for (int idx = j; idx < nu * 25; idx += 256) {
        const int ul = idx / 25;
        const int p = idx - ul * 25;
        const int u = ubeg + ul;
        float s, c;
        __sincosf(k2pi * (float)((u * (p + 244)) & 255), &s, &c);
        T[ul][p] = make_float2(c, s);
    }

    const float2* src = FBtmp + (size_t)img * 6400 + j;
    float2 S[25];
#pragma unroll
    for (int p = 0; p < 25; ++p) S[p] = src[p * 256];
    __syncthreads();

    float2* dst = FBh + (size_t)img * 33024 + j;
    for (int ul = 0; ul < nu; ++ul) {
        float2 a0 = make_float2(0.f, 0.f);
        float2 a1 = make_float2(0.f, 0.f);
#pragma unroll
        for (int p = 0; p < 25; ++p) {
            const float2 t = T[ul][p];
            const float2 s = S[p];
            if (p & 1) {
                a1.x = fmaf(t.x, s.x, fmaf(-t.y, s.y, a1.x));
                a1.y = fmaf(t.x, s.y, fmaf(t.y, s.x, a1.y));
            } else {
                a0.x = fmaf(t.x, s.x, fmaf(-t.y, s.y, a0.x));
                a0.y = fmaf(t.x, s.y, fmaf(t.y, s.x, a0.y));
            }
        }
        dst[(size_t)(ubeg + ul) * 256] = make_float2(a0.x + a1.x, a0.y + a1.y);
    }
}

// K6: fused M + FX build + radix-4 row IFFT + Hermitian column fold.
// Block = (img, p-pair {pa=2b, pb=2b+1}), 4 row slots x 64 lanes; each wave
// owns one row -> FFT stages are wave-local, no barriers needed.
__global__ __launch_bounds__(256) void k6_fused(const float2* __restrict__ FBh,
                                                const float2* __restrict__ Fx,
                                                const float* __restrict__ alpha,
                                                float2* __restrict__ Zf) {
    __shared__ float2 stage[4][256];     // FBh rows pa,128-pa,pb,128-pb
    __shared__ float2 buf[2][4][288];    // padded: PHI(i)=i+(i>>3)
    __shared__ float2 tw[192];           // e^{+i pi k/128}, k<192
    const int tid = threadIdx.x;
    const int rs = tid >> 6;             // row slot = wave id
    const int q = tid & 63;
    const int img = blockIdx.x / 33;
    const int bq = blockIdx.x % 33;
    const int pa = 2 * bq;
    const int pb = (pa + 1 < 65) ? (pa + 1) : 64;   // last block: pb==pa==64
    for (int i = tid; i < 192; i += 256) {
        float s, c;
        __sincosf((float)M_PI * (float)i / 128.f, &s, &c);
        tw[i] = make_float2(c, s);
    }
    {
        const float2* base = FBh + (size_t)img * 33024;
        stage[0][tid] = base[pa * 256 + tid];
        stage[1][tid] = base[(128 - pa) * 256 + tid];
        stage[2][tid] = base[pb * 256 + tid];
        stage[3][tid] = base[(128 - pb) * 256 + tid];
    }
    __syncthreads();  // BARRIER 1: stage[] + tw[] visible to all waves

    const int p = (rs < 2) ? pa : pb;
    const int sb = rs & 2;
    const int u = ((rs & 1) == 0) ? p : (128 - p);   // 0..128
    const int um = u & 127;
    const int msel = (um == p) ? 0 : 1;
    const int mi = sb | msel;
    const int oi = sb | (1 - msel);

    const float ci = tw[um].x, si = -tw[um].y;
    const float b = 1.f / (1.f + __expf(9.f - alpha[img & 63])) + 1e-3f;
    const float scale = 1.f / 65536.f;
    const float2 Di0 = make_float2(1.f + ci, si);
    const float2 Di1 = make_float2(1.f - ci, -si);
    const float2 Du = (u < 128) ? Di0 : Di1;
#pragma unroll
    for (int h = 0; h < 2; ++h) {
        const int t = q + 64 * h;        // 0..127
        float2 f00 = stage[mi][t];
        float2 f01 = stage[mi][t + 128];
        float2 f10, f11;
        if (um == 0) {  // rows {0,128}: row 128 direct
            f10 = stage[oi][t];
            f11 = stage[oi][t + 128];
        } else {
            f10 = conjf2(stage[oi][(256 - t) & 255]);
            f11 = conjf2(stage[oi][128 - t]);
        }
        float2 fx = Fx[(size_t)img * 16384 + um * 128 + t];
        const float cj = tw[t].x, sj = -tw[t].y;
        float2 Dj0 = make_float2(1.f + cj, sj);
        float2 Dj1 = make_float2(1.f - cj, -sj);
        // S1 = (f00*Dj0 + f01*Dj1)*Di0 + (f10*Dj0 + f11*Dj1)*Di1  (6 cmuls)
        float2 A = cadd(cmul(f00, Dj0), cmul(f01, Dj1));
        float2 Bt = cadd(cmul(f10, Dj0), cmul(f11, Dj1));
        float2 S1 = cadd(cmul(A, Di0), cmul(Bt, Di1));
        S1.x *= 0.25f;
        S1.y *= 0.25f;
        float S2 = 0.25f * (f00.x * f00.x + f00.y * f00.y + f01.x * f01.x + f01.y * f01.y +
                            f10.x * f10.x + f10.y * f10.y + f11.x * f11.x + f11.y * f11.y);
        float inv = 1.f / (S2 + b);
        float2 mm = make_float2((1.f - S1.x) * inv, (-S1.y) * inv);
        float2 c0v = (u < 128) ? f00 : f10;
        float2 c1v = (u < 128) ? f01 : f11;
        float2 t0 = cadd(cmul(conjf2(c0v), mm), cmul(Du, Dj0));
        float2 t1 = cadd(cmul(conjf2(c1v), mm), cmul(Du, Dj1));
        float2 FX0 = cmul(fx, t0);
        float2 FX1 = cmul(fx, t1);
        buf[0][rs][PHI(t)] = make_float2(FX0.x * scale, FX0.y * scale);
        buf[0][rs][PHI(t + 128)] = make_float2(FX1.x * scale, FX1.y * scale);
    }

    // radix-4 Stockham IFFT (sigma=+1), wave-local: no barriers.
    int cur = 0, m = 1;
#pragma unroll
    for (int st = 0; st < 4; ++st) {
        const int k = q & (m - 1);
        const int jm = q - k;
        const float2 w1 = tw[jm];
        const float2 w2 = tw[2 * jm];
        const float2 w3 = tw[3 * jm];
        float2 a0 = buf[cur][rs][PHI(q)];
        float2 a1 = buf[cur][rs][PHI(q + 64)];
        float2 a2 = buf[cur][rs][PHI(q + 128)];
        float2 a3 = buf[cur][rs][PHI(q + 192)];
        float2 s02 = cadd(a0, a2), d02 = csub(a0, a2);
        float2 s13 = cadd(a1, a3), d13 = csub(a1, a3);
        float2 b0 = cadd(s02, s13), b2v = csub(s02, s13);
        float2 b1 = make_float2(d02.x - d13.y, d02.y + d13.x);   // d02 + i*d13
        float2 b3 = make_float2(d02.x + d13.y, d02.y - d13.x);   // d02 - i*d13
        const int o = 4 * jm + k;
        buf[cur ^ 1][rs][PHI(o)] = b0;
        buf[cur ^ 1][rs][PHI(o + m)] = cmul(w1, b1);
        buf[cur ^ 1][rs][PHI(o + 2 * m)] = cmul(w2, b2v);
        buf[cur ^ 1][rs][PHI(o + 3 * m)] = cmul(w3, b3);
        cur ^= 1;
        m <<= 2;
    }
    __syncthreads();  // BARRIER 2: cross-wave fold reads rs^1

    // Hermitian fold: Zf[u0] = (Z[u0]+conj(Z[128-u0])) + i*w.(Z[u0]-conj(Z[128-u0]))
    const int u0 = u;
    bool dowrite = ((rs & 1) == 0) ? true : (p > 0 && p < 64);
    if (pb == pa && rs >= 2) dowrite = false;  // last-block dedup
    if (dowrite) {
        const float2 w = tw[u0];
        float2* zb = Zf + (size_t)img * 32768 + (size_t)u0 * 256;
#pragma unroll
        for (int hh = 0; hh < 4; ++hh) {
            const int jj = q + 64 * hh;
            float2 su = buf[cur][rs][PHI(jj)];
            float2 s2 = buf[cur][rs ^ 1][PHI(jj)];
            float2 e = make_float2(su.x + s2.x, su.y - s2.y);   // su + conj(s2)
            float2 o_ = make_float2(su.x - s2.x, su.y + s2.y);  // su - conj(s2)
            float2 wo = cmul(w, o_);
            zb[jj] = make_float2(e.x - wo.y, e.y + wo.x);       // e + i*wo
        }
    }
}

// K7: pure C2R column IFFT (radix-4), 16 cols/block, fold already in k6.
__global__ __launch_bounds__(256) void k7_c2r(const float2* __restrict__ Zf,
                                              float* __restrict__ out) {
    __shared__ float2 buf[2][128][16];
    __shared__ float2 tw[96];  // e^{+i pi k/64}
    const int tid = threadIdx.x;
    const int img = blockIdx.x >> 4;
    const int c0 = (blockIdx.x & 15) * 16;
    for (int i = tid; i < 96; i += 256) {
        float s, c;
        __sincosf((float)M_PI * (float)i / 64.f, &s, &c);
        tw[i] = make_float2(c, s);
    }
    const float2* zb = Zf + (size_t)img * 32768 + c0;
    for (int it = 0; it < 8; ++it) {
        int idx = it * 256 + tid;
        buf[0][idx >> 4][idx & 15] = zb[(idx >> 4) * 256 + (idx & 15)];
    }
    int cur = fft4_cols_128<1, 256>(buf, tw);
    float* ob = out + (size_t)img * 65536 + c0;
    for (int it = 0; it < 8; ++it) {
        int idx = it * 256 + tid;
        int n = idx >> 4, c = idx & 15;
        float2 y = buf[cur][n][c];
        ob[(2 * n) * 256 + c] = y.x;
        ob[(2 * n + 1) * 256 + c] = y.y;
    }
}

extern "C" void kernel_launch(void* const* d_in, const int* in_sizes, int n_in,
                              void* d_out, int out_size, void* d_ws, size_t ws_size,
                              hipStream_t stream) {
    const float* x = (const float*)d_in[0];      // (4,64,128,128)
    const float* k = (const float*)d_in[1];      // (4,64,25,25)
    const float* alpha = (const float*)d_in[2];  // (1,64,1,1)
    float* out = (float*)d_out;                  // (4,64,256,256)

    float2* Fx = (float2*)d_ws;           // 256*16384   = 32 MB
    float2* FBh = Fx + 256 * 16384;       // 256*129*256 = 67.6 MB
    float2* Zf = FBh + 256 * 33024;       // 256*128*256 = 64 MB (folded)
    float2* FBtmp = Zf + 256 * 32768;     // 256*25*256  = 13.1 MB

    hipLaunchKernelGGL(k1_fft_rows_x, dim3(4096), dim3(256), 0, stream, x, Fx);
    hipLaunchKernelGGL(k2_fft_cols_x, dim3(2048), dim3(256), 0, stream, Fx);
    hipLaunchKernelGGL(k3_fft_rows_k, dim3(6400), dim3(128), 0, stream, k, FBtmp);
    hipLaunchKernelGGL(k4_dft_cols_k, dim3(1024), dim3(256), 0, stream, FBtmp, FBh);
    hipLaunchKernelGGL(k6_fused, dim3(256 * 33), dim3(256), 0, stream, FBh, Fx, alpha, Zf);
    hipLaunchKernelGGL(k7_c2r, dim3(4096), dim3(256), 0, stream, Zf, out);
}

// Round 4
// 190.498 us; speedup vs baseline: 1.2216x; 1.0195x over previous
//
#include <hip/hip_runtime.h>
#include <math.h>

// Closed-form pipeline with Hermitian (real-output) symmetry:
//   Fx  = fft2_128(x), stored cols 0..64 only (x real -> 2D-Hermitian)
//   FBh = fft2_256(pad+roll(k)) rows 0..128  (k3 rows, k4 LDS-table col DFT)
//   k6 fused: stage 4 FBh rows; M=(1-S1)/(S2+b); FX rows; radix-4 row IFFT
//             (wave-local, barrier-free); Hermitian fold; write Zf[0..127]
//   k7: pure 128-pt C2R column IFFT of Zf (wave-local radix-4)
// R7: j-invariant twiddles -> cooperative LDS twiddle tables everywhere.
// R8: single HB-table serves all Stockham stages; fold moved into k6.
// R9: radix-4 Stockham; k6 wave-owns-row -> no barriers in FFT loop.
// R10: (a) Fx 2D-Hermitian halving: k1 writes cols 0..64 only; k2 runs 5
//        col-tiles (was 8); k6 mirrors t>64 via conj(Fx[(128-um)&127][128-t]).
//      (b) k2/k7 column FFTs wave-local: each wave owns 4 cols in [col][130]
//        layout (pad -> 2-way on staging, 4-way=8B floor on butterflies);
//        barriers 5 -> 2 (post-load, pre-store).

static __device__ __forceinline__ float2 cmul(float2 a, float2 b) {
    return make_float2(a.x * b.x - a.y * b.y, a.x * b.y + a.y * b.x);
}
static __device__ __forceinline__ float2 cadd(float2 a, float2 b) {
    return make_float2(a.x + b.x, a.y + b.y);
}
static __device__ __forceinline__ float2 csub(float2 a, float2 b) {
    return make_float2(a.x - b.x, a.y - b.y);
}
static __device__ __forceinline__ float2 conjf2(float2 a) {
    return make_float2(a.x, -a.y);
}
static __device__ __forceinline__ int PHI(int i) { return i + (i >> 3); }

// Fill tw[i] = (cos(SIGN*pi*i/HB), sin(SIGN*pi*i/HB)) for i in [0,HB).
template <int HB, int SIGN, int THREADS>
static __device__ __forceinline__ void fill_tw(float2* tw) {
    for (int i = threadIdx.x; i < HB; i += THREADS) {
        float s, c;
        __sincosf((float)SIGN * (float)M_PI * (float)i / (float)HB, &s, &c);
        tw[i] = make_float2(c, s);
    }
}

// ---------------- radix-2 Stockham rows (k1/k3) ----------------
template <int N, int R, int SIGN>
static __device__ __forceinline__ int fft_lds_rows(float2 (&buf)[2][R][N],
                                                   const float2* __restrict__ tw) {
    constexpr int HB = N / 2;
    const int tid = threadIdx.x;
    const int row = tid / HB;
    const int bt = tid % HB;
    int cur = 0, m = 1;
    for (int l = HB; l >= 1; l >>= 1) {
        __syncthreads();
        const int k = bt & (m - 1);
        const float2 w = tw[bt - k];
        float2 a = buf[cur][row][bt];
        float2 b = buf[cur][row][bt + HB];
        float2 d = make_float2(a.x - b.x, a.y - b.y);
        float2 wd = make_float2(w.x * d.x - w.y * d.y, w.x * d.y + w.y * d.x);
        const int o = 2 * bt - k;
        buf[cur ^ 1][row][o] = make_float2(a.x + b.x, a.y + b.y);
        buf[cur ^ 1][row][o + m] = wd;
        cur ^= 1;
        m <<= 1;
    }
    __syncthreads();
    return cur;
}

// ------------- wave-local mixed radix-4/2 128-pt column FFT -------------
// Each wave owns 4 adjacent cols; layout buf[2][NCOL][130] ([col][bt], pad).
// lane = 16*cl + r: cl = col-within-wave, r = butterfly lane. No internal
// barriers: all writers of a column are in the same wave (in-order DS).
// tw[i] = e^{SIGN*i*pi/64}, i < 96.
template <int SIGN, int NCOL>
static __device__ __forceinline__ int fft4_cols_wavelocal(float2 (&buf)[2][NCOL][130],
                                                          const float2* __restrict__ tw) {
    const int lane = threadIdx.x & 63;
    const int wv = threadIdx.x >> 6;
    const int col = wv * 4 + (lane >> 4);
    const int r = lane & 15;
    int cur = 0, m = 1;
#pragma unroll
    for (int st = 0; st < 3; ++st) {
#pragma unroll
        for (int b = 0; b < 2; ++b) {
            const int bq = r + 16 * b;
            const int k = bq & (m - 1);
            const int jm = bq - k;
            const float2 w1 = tw[jm];
            const float2 w2 = tw[2 * jm];
            const float2 w3 = tw[3 * jm];
            float2 a0 = buf[cur][col][bq];
            float2 a1 = buf[cur][col][bq + 32];
            float2 a2 = buf[cur][col][bq + 64];
            float2 a3 = buf[cur][col][bq + 96];
            float2 s02 = cadd(a0, a2), d02 = csub(a0, a2);
            float2 s13 = cadd(a1, a3), d13 = csub(a1, a3);
            float2 b0 = cadd(s02, s13), b2 = csub(s02, s13);
            float2 b1 = make_float2(d02.x - (float)SIGN * d13.y,
                                    d02.y + (float)SIGN * d13.x);
            float2 b3 = make_float2(d02.x + (float)SIGN * d13.y,
                                    d02.y - (float)SIGN * d13.x);
            const int o = 4 * jm + k;
            buf[cur ^ 1][col][o] = b0;
            buf[cur ^ 1][col][o + m] = cmul(w1, b1);
            buf[cur ^ 1][col][o + 2 * m] = cmul(w2, b2);
            buf[cur ^ 1][col][o + 3 * m] = cmul(w3, b3);
        }
        cur ^= 1;
        m <<= 2;
    }
#pragma unroll
    for (int b = 0; b < 4; ++b) {  // radix-2 tail, m=64, j=0
        const int bt = r + 16 * b;
        float2 a = buf[cur][col][bt];
        float2 bb = buf[cur][col][bt + 64];
        buf[cur ^ 1][col][bt] = cadd(a, bb);
        buf[cur ^ 1][col][bt + 64] = csub(a, bb);
    }
    return cur ^ 1;
}

// K1: row FFT of x (N=128) with pack-2; write only cols 0..64 (Hermitian).
__global__ __launch_bounds__(256) void k1_fft_rows_x(const float* __restrict__ x,
                                                     float2* __restrict__ Fx) {
    __shared__ float2 buf[2][4][128];
    __shared__ float2 tw64m[64];
    const int tid = threadIdx.x;
    const int row = tid >> 6;   // pair slot 0..3
    const int t = tid & 63;
    fill_tw<64, -1, 256>(tw64m);
    const int gpair = blockIdx.x * 4 + row;  // img*64 + pr
    const float* r0 = x + (size_t)gpair * 256;        // row 2*pr (128 floats)
    const float* r1 = r0 + 128;                       // row 2*pr+1
    const float2 a0 = ((const float2*)r0)[t];
    const float2 a1 = ((const float2*)r1)[t];
    buf[0][row][2 * t].x = a0.x;
    buf[0][row][2 * t].y = a1.x;
    buf[0][row][2 * t + 1].x = a0.y;
    buf[0][row][2 * t + 1].y = a1.y;
    int cur = fft_lds_rows<128, 4, -1>(buf, tw64m);
    float2* d0 = Fx + (size_t)gpair * 256;            // Fx row 2*pr
    float2* d1 = d0 + 128;
    for (int h = 0; h < 2; ++h) {
        int tt = t + h * 64;
        if (tt > 64) continue;  // Hermitian: cols 65..127 reconstructed in k6
        float2 Zt = buf[cur][row][tt];
        float2 Zm = buf[cur][row][(128 - tt) & 127];
        d0[tt] = make_float2(0.5f * (Zt.x + Zm.x), 0.5f * (Zt.y - Zm.y));
        float ax = Zt.x - Zm.x, ay = Zt.y + Zm.y;
        d1[tt] = make_float2(0.5f * ay, -0.5f * ax);
    }
}

// K2: column FFT of Fx, in place, cols 0..64 only -> 5 tiles of 16.
// (tile 4 also transforms garbage cols 65..79 -- written, never read.)
__global__ __launch_bounds__(256) void k2_fft_cols_x(float2* __restrict__ Fx) {
    __shared__ float2 buf[2][16][130];
    __shared__ float2 tw[96];
    const int tid = threadIdx.x;
    const int img = blockIdx.x / 5;
    const int c0 = (blockIdx.x % 5) * 16;
    for (int i = tid; i < 96; i += 256) {
        float s, c;
        __sincosf(-(float)M_PI * (float)i / 64.f, &s, &c);
        tw[i] = make_float2(c, s);
    }
    float2* base = Fx + (size_t)img * 16384 + c0;
    for (int it = 0; it < 8; ++it) {
        int idx = it * 256 + tid;
        int rr = idx >> 4, cc = idx & 15;
        buf[0][cc][rr] = base[rr * 128 + cc];
    }
    __syncthreads();
    int cur = fft4_cols_wavelocal<-1, 16>(buf, tw);
    __syncthreads();
    for (int it = 0; it < 8; ++it) {
        int idx = it * 256 + tid;
        int rr = idx >> 4, cc = idx & 15;
        base[rr * 128 + cc] = buf[cur][cc][rr];
    }
}

// K3: row FFT of padded+rolled psf (N=256), compact output [img][25][256].
__global__ __launch_bounds__(128) void k3_fft_rows_k(const float* __restrict__ kin,
                                                     float2* __restrict__ FBtmp) {
    __shared__ float2 buf[2][1][256];
    __shared__ float2 tw128m[128];
    const int tid = threadIdx.x;  // 128
    const int img = blockIdx.x / 25;
    const int lr = blockIdx.x % 25;
    fill_tw<128, -1, 128>(tw128m);
    const float* krow = kin + img * 625 + lr * 25;
    for (int h = 0; h < 2; ++h) {
        int v = tid + h * 128;
        int pc = (v + 12) & 255;
        buf[0][0][v] = make_float2(pc < 25 ? krow[pc] : 0.f, 0.f);
    }
    int cur = fft_lds_rows<256, 1, -1>(buf, tw128m);
    float2* dst = FBtmp + (size_t)img * 6400 + lr * 256;
    dst[tid] = buf[cur][0][tid];
    dst[tid + 128] = buf[cur][0][tid + 128];
}

// K4: column DFT via cooperative LDS twiddle table (R7).
__global__ __launch_bounds__(256) void k4_dft_cols_k(const float2* __restrict__ FBtmp,
                                                     float2* __restrict__ FBh) {
    __shared__ float2 T[33][28];
    const int j = threadIdx.x;
    const int img = blockIdx.x >> 2;
    const int q = blockIdx.x & 3;
    const int ubeg = q * 33;
    const int nu = (ubeg + 33 < 129) ? 33 : (129 - ubeg);
    const float k2pi = -2.f * (float)M_PI / 256.f;

    for (int idx = j; idx < nu * 25; idx += 256) {
        const int ul = idx / 25;
        const int p = idx - ul * 25;
        const int u = ubeg + ul;
        float s, c;
        __sincosf(k2pi * (float)((u * (p + 244)) & 255), &s, &c);
        T[ul][p] = make_float2(c, s);
    }

    const float2* src = FBtmp + (size_t)img * 6400 + j;
    float2 S[25];
#pragma unroll
    for (int p = 0; p < 25; ++p) S[p] = src[p * 256];
    __syncthreads();

    float2* dst = FBh + (size_t)img * 33024 + j;
    for (int ul = 0; ul < nu; ++ul) {
        float2 a0 = make_float2(0.f, 0.f);
        float2 a1 = make_float2(0.f, 0.f);
#pragma unroll
        for (int p = 0; p < 25; ++p) {
            const float2 t = T[ul][p];
            const float2 s = S[p];
            if (p & 1) {
                a1.x = fmaf(t.x, s.x, fmaf(-t.y, s.y, a1.x));
                a1.y = fmaf(t.x, s.y, fmaf(t.y, s.x, a1.y));
            } else {
                a0.x = fmaf(t.x, s.x, fmaf(-t.y, s.y, a0.x));
                a0.y = fmaf(t.x, s.y, fmaf(t.y, s.x, a0.y));
            }
        }
        dst[(size_t)(ubeg + ul) * 256] = make_float2(a0.x + a1.x, a0.y + a1.y);
    }
}

// K6: fused M + FX build + radix-4 row IFFT + Hermitian column fold.
// Block = (img, p-pair {pa=2b, pb=2b+1}), 4 row slots x 64 lanes; each wave
// owns one row -> FFT stages are wave-local, no barriers needed.
__global__ __launch_bounds__(256) void k6_fused(const float2* __restrict__ FBh,
                                                const float2* __restrict__ Fx,
                                                const float* __restrict__ alpha,
                                                float2* __restrict__ Zf) {
    __shared__ float2 stage[4][256];     // FBh rows pa,128-pa,pb,128-pb
    __shared__ float2 buf[2][4][288];    // padded: PHI(i)=i+(i>>3)
    __shared__ float2 tw[192];           // e^{+i pi k/128}, k<192
    const int tid = threadIdx.x;
    const int rs = tid >> 6;             // row slot = wave id
    const int q = tid & 63;
    const int img = blockIdx.x / 33;
    const int bq = blockIdx.x % 33;
    const int pa = 2 * bq;
    const int pb = (pa + 1 < 65) ? (pa + 1) : 64;   // last block: pb==pa==64
    for (int i = tid; i < 192; i += 256) {
        float s, c;
        __sincosf((float)M_PI * (float)i / 128.f, &s, &c);
        tw[i] = make_float2(c, s);
    }
    {
        const float2* base = FBh + (size_t)img * 33024;
        stage[0][tid] = base[pa * 256 + tid];
        stage[1][tid] = base[(128 - pa) * 256 + tid];
        stage[2][tid] = base[pb * 256 + tid];
        stage[3][tid] = base[(128 - pb) * 256 + tid];
    }
    __syncthreads();  // BARRIER 1: stage[] + tw[] visible to all waves

    const int p = (rs < 2) ? pa : pb;
    const int sb = rs & 2;
    const int u = ((rs & 1) == 0) ? p : (128 - p);   // 0..128
    const int um = u & 127;
    const int msel = (um == p) ? 0 : 1;
    const int mi = sb | msel;
    const int oi = sb | (1 - msel);

    const float ci = tw[um].x, si = -tw[um].y;
    const float b = 1.f / (1.f + __expf(9.f - alpha[img & 63])) + 1e-3f;
    const float scale = 1.f / 65536.f;
    const float2 Di0 = make_float2(1.f + ci, si);
    const float2 Di1 = make_float2(1.f - ci, -si);
    const float2 Du = (u < 128) ? Di0 : Di1;
#pragma unroll
    for (int h = 0; h < 2; ++h) {
        const int t = q + 64 * h;        // 0..127
        float2 f00 = stage[mi][t];
        float2 f01 = stage[mi][t + 128];
        float2 f10, f11;
        if (um == 0) {  // rows {0,128}: row 128 direct
            f10 = stage[oi][t];
            f11 = stage[oi][t + 128];
        } else {
            f10 = conjf2(stage[oi][(256 - t) & 255]);
            f11 = conjf2(stage[oi][128 - t]);
        }
        // Fx stored cols 0..64 only; mirror t>64: conj(Fx[(128-um)%128][128-t])
        const bool mir = (t > 64);
        const int rr = mir ? ((128 - um) & 127) : um;
        const int cc = mir ? (128 - t) : t;
        float2 fx = Fx[(size_t)img * 16384 + rr * 128 + cc];
        if (mir) fx.y = -fx.y;
        const float cj = tw[t].x, sj = -tw[t].y;
        float2 Dj0 = make_float2(1.f + cj, sj);
        float2 Dj1 = make_float2(1.f - cj, -sj);
        // S1 = (f00*Dj0 + f01*Dj1)*Di0 + (f10*Dj0 + f11*Dj1)*Di1  (6 cmuls)
        float2 A = cadd(cmul(f00, Dj0), cmul(f01, Dj1));
        float2 Bt = cadd(cmul(f10, Dj0), cmul(f11, Dj1));
        float2 S1 = cadd(cmul(A, Di0), cmul(Bt, Di1));
        S1.x *= 0.25f;
        S1.y *= 0.25f;
        float S2 = 0.25f * (f00.x * f00.x + f00.y * f00.y + f01.x * f01.x + f01.y * f01.y +
                            f10.x * f10.x + f10.y * f10.y + f11.x * f11.x + f11.y * f11.y);
        float inv = 1.f / (S2 + b);
        float2 mm = make_float2((1.f - S1.x) * inv, (-S1.y) * inv);
        float2 c0v = (u < 128) ? f00 : f10;
        float2 c1v = (u < 128) ? f01 : f11;
        float2 t0 = cadd(cmul(conjf2(c0v), mm), cmul(Du, Dj0));
        float2 t1 = cadd(cmul(conjf2(c1v), mm), cmul(Du, Dj1));
        float2 FX0 = cmul(fx, t0);
        float2 FX1 = cmul(fx, t1);
        buf[0][rs][PHI(t)] = make_float2(FX0.x * scale, FX0.y * scale);
        buf[0][rs][PHI(t + 128)] = make_float2(FX1.x * scale, FX1.y * scale);
    }

    // radix-4 Stockham IFFT (sigma=+1), wave-local: no barriers.
    int cur = 0, m = 1;
#pragma unroll
    for (int st = 0; st < 4; ++st) {
        const int k = q & (m - 1);
        const int jm = q - k;
        const float2 w1 = tw[jm];
        const float2 w2 = tw[2 * jm];
        const float2 w3 = tw[3 * jm];
        float2 a0 = buf[cur][rs][PHI(q)];
        float2 a1 = buf[cur][rs][PHI(q + 64)];
        float2 a2 = buf[cur][rs][PHI(q + 128)];
        float2 a3 = buf[cur][rs][PHI(q + 192)];
        float2 s02 = cadd(a0, a2), d02 = csub(a0, a2);
        float2 s13 = cadd(a1, a3), d13 = csub(a1, a3);
        float2 b0 = cadd(s02, s13), b2v = csub(s02, s13);
        float2 b1 = make_float2(d02.x - d13.y, d02.y + d13.x);   // d02 + i*d13
        float2 b3 = make_float2(d02.x + d13.y, d02.y - d13.x);   // d02 - i*d13
        const int o = 4 * jm + k;
        buf[cur ^ 1][rs][PHI(o)] = b0;
        buf[cur ^ 1][rs][PHI(o + m)] = cmul(w1, b1);
        buf[cur ^ 1][rs][PHI(o + 2 * m)] = cmul(w2, b2v);
        buf[cur ^ 1][rs][PHI(o + 3 * m)] = cmul(w3, b3);
        cur ^= 1;
        m <<= 2;
    }
    __syncthreads();  // BARRIER 2: cross-wave fold reads rs^1

    // Hermitian fold: Zf[u0] = (Z[u0]+conj(Z[128-u0])) + i*w.(Z[u0]-conj(Z[128-u0]))
    const int u0 = u;
    bool dowrite = ((rs & 1) == 0) ? true : (p > 0 && p < 64);
    if (pb == pa && rs >= 2) dowrite = false;  // last-block dedup
    if (dowrite) {
        const float2 w = tw[u0];
        float2* zb = Zf + (size_t)img * 32768 + (size_t)u0 * 256;
#pragma unroll
        for (int hh = 0; hh < 4; ++hh) {
            const int jj = q + 64 * hh;
            float2 su = buf[cur][rs][PHI(jj)];
            float2 s2 = buf[cur][rs ^ 1][PHI(jj)];
            float2 e = make_float2(su.x + s2.x, su.y - s2.y);   // su + conj(s2)
            float2 o_ = make_float2(su.x - s2.x, su.y + s2.y);  // su - conj(s2)
            float2 wo = cmul(w, o_);
            zb[jj] = make_float2(e.x - wo.y, e.y + wo.x);       // e + i*wo
        }
    }
}

// K7: pure C2R column IFFT (wave-local radix-4), 16 cols/block.
__global__ __launch_bounds__(256) void k7_c2r(const float2* __restrict__ Zf,
                                              float* __restrict__ out) {
    __shared__ float2 buf[2][16][130];
    __shared__ float2 tw[96];  // e^{+i pi k/64}
    const int tid = threadIdx.x;
    const int img = blockIdx.x >> 4;
    const int c0 = (blockIdx.x & 15) * 16;
    for (int i = tid; i < 96; i += 256) {
        float s, c;
        __sincosf((float)M_PI * (float)i / 64.f, &s, &c);
        tw[i] = make_float2(c, s);
    }
    const float2* zb = Zf + (size_t)img * 32768 + c0;
    for (int it = 0; it < 8; ++it) {
        int idx = it * 256 + tid;
        int rr = idx >> 4, cc = idx & 15;
        buf[0][cc][rr] = zb[rr * 256 + cc];
    }
    __syncthreads();
    int cur = fft4_cols_wavelocal<1, 16>(buf, tw);
    __syncthreads();
    float* ob = out + (size_t)img * 65536 + c0;
    for (int it = 0; it < 8; ++it) {
        int idx = it * 256 + tid;
        int n = idx >> 4, c = idx & 15;
        float2 y = buf[cur][c][n];
        ob[(2 * n) * 256 + c] = y.x;
        ob[(2 * n + 1) * 256 + c] = y.y;
    }
}

extern "C" void kernel_launch(void* const* d_in, const int* in_sizes, int n_in,
                              void* d_out, int out_size, void* d_ws, size_t ws_size,
                              hipStream_t stream) {
    const float* x = (const float*)d_in[0];      // (4,64,128,128)
    const float* k = (const float*)d_in[1];      // (4,64,25,25)
    const float* alpha = (const float*)d_in[2];  // (1,64,1,1)
    float* out = (float*)d_out;                  // (4,64,256,256)

    float2* Fx = (float2*)d_ws;           // 256*16384   = 32 MB (cols 0..64 live)
    float2* FBh = Fx + 256 * 16384;       // 256*129*256 = 67.6 MB
    float2* Zf = FBh + 256 * 33024;       // 256*128*256 = 64 MB (folded)
    float2* FBtmp = Zf + 256 * 32768;     // 256*25*256  = 13.1 MB

    hipLaunchKernelGGL(k1_fft_rows_x, dim3(4096), dim3(256), 0, stream, x, Fx);
    hipLaunchKernelGGL(k2_fft_cols_x, dim3(256 * 5), dim3(256), 0, stream, Fx);
    hipLaunchKernelGGL(k3_fft_rows_k, dim3(6400), dim3(128), 0, stream, k, FBtmp);
    hipLaunchKernelGGL(k4_dft_cols_k, dim3(1024), dim3(256), 0, stream, FBtmp, FBh);
    hipLaunchKernelGGL(k6_fused, dim3(256 * 33), dim3(256), 0, stream, FBh, Fx, alpha, Zf);
    hipLaunchKernelGGL(k7_c2r, dim3(4096), dim3(256), 0, stream, Zf, out);
}

// Round 5
// 185.105 us; speedup vs baseline: 1.2572x; 1.0291x over previous
//
#include <hip/hip_runtime.h>
#include <math.h>

// Closed-form pipeline with Hermitian (real-output) symmetry:
//   Fx  = fft2_128(x), stored cols 0..64 only (x real -> 2D-Hermitian)
//   FBtmp = row FFTs (N=256) of 25 psf rows (k3)
//   k6 fused: per-block on-the-fly column DFT of FBtmp -> 4 FBh rows
//             {pa,128-pa,pb,128-pb} (R11: k4 deleted, FBh never materialized);
//             M=(1-S1)/(S2+b); FX rows; radix-4 row IFFT (wave-local,
//             barrier-free); Hermitian fold; write Zf[0..127]
//   k7: pure 128-pt C2R column IFFT of Zf (wave-local radix-4)
// R7: j-invariant twiddles -> cooperative LDS twiddle tables everywhere.
// R8: single HB-table serves all Stockham stages; fold moved into k6.
// R9: radix-4 Stockham; k6 wave-owns-row -> no barriers in FFT loop.
// R10: Fx 2D-Hermitian halving; k2/k7 wave-local columns ([col][130] pad).
// R11: FBh round-trip (66 MB write + 66 MB read) eliminated: k6 computes
//   its 4 rows from FBtmp (51.2 KB/img, L2/L3-resident) via 25-tap dots.
//   Mirror rows free: FBh[128-u][j] = sum_p (-1)^p S[p] conj(T_u[p]) --
//   same 4 products as +u, recombined (12 VALU/tap for the pair).

static __device__ __forceinline__ float2 cmul(float2 a, float2 b) {
    return make_float2(a.x * b.x - a.y * b.y, a.x * b.y + a.y * b.x);
}
static __device__ __forceinline__ float2 cadd(float2 a, float2 b) {
    return make_float2(a.x + b.x, a.y + b.y);
}
static __device__ __forceinline__ float2 csub(float2 a, float2 b) {
    return make_float2(a.x - b.x, a.y - b.y);
}
static __device__ __forceinline__ float2 conjf2(float2 a) {
    return make_float2(a.x, -a.y);
}
static __device__ __forceinline__ int PHI(int i) { return i + (i >> 3); }

// Fill tw[i] = (cos(SIGN*pi*i/HB), sin(SIGN*pi*i/HB)) for i in [0,HB).
template <int HB, int SIGN, int THREADS>
static __device__ __forceinline__ void fill_tw(float2* tw) {
    for (int i = threadIdx.x; i < HB; i += THREADS) {
        float s, c;
        __sincosf((float)SIGN * (float)M_PI * (float)i / (float)HB, &s, &c);
        tw[i] = make_float2(c, s);
    }
}

// ---------------- radix-2 Stockham rows (k1/k3) ----------------
template <int N, int R, int SIGN>
static __device__ __forceinline__ int fft_lds_rows(float2 (&buf)[2][R][N],
                                                   const float2* __restrict__ tw) {
    constexpr int HB = N / 2;
    const int tid = threadIdx.x;
    const int row = tid / HB;
    const int bt = tid % HB;
    int cur = 0, m = 1;
    for (int l = HB; l >= 1; l >>= 1) {
        __syncthreads();
        const int k = bt & (m - 1);
        const float2 w = tw[bt - k];
        float2 a = buf[cur][row][bt];
        float2 b = buf[cur][row][bt + HB];
        float2 d = make_float2(a.x - b.x, a.y - b.y);
        float2 wd = make_float2(w.x * d.x - w.y * d.y, w.x * d.y + w.y * d.x);
        const int o = 2 * bt - k;
        buf[cur ^ 1][row][o] = make_float2(a.x + b.x, a.y + b.y);
        buf[cur ^ 1][row][o + m] = wd;
        cur ^= 1;
        m <<= 1;
    }
    __syncthreads();
    return cur;
}

// ------------- wave-local mixed radix-4/2 128-pt column FFT -------------
// Each wave owns 4 adjacent cols; layout buf[2][NCOL][130] ([col][bt], pad).
// No internal barriers: all writers of a column are in the same wave.
// tw[i] = e^{SIGN*i*pi/64}, i < 96.
template <int SIGN, int NCOL>
static __device__ __forceinline__ int fft4_cols_wavelocal(float2 (&buf)[2][NCOL][130],
                                                          const float2* __restrict__ tw) {
    const int lane = threadIdx.x & 63;
    const int wv = threadIdx.x >> 6;
    const int col = wv * 4 + (lane >> 4);
    const int r = lane & 15;
    int cur = 0, m = 1;
#pragma unroll
    for (int st = 0; st < 3; ++st) {
#pragma unroll
        for (int b = 0; b < 2; ++b) {
            const int bq = r + 16 * b;
            const int k = bq & (m - 1);
            const int jm = bq - k;
            const float2 w1 = tw[jm];
            const float2 w2 = tw[2 * jm];
            const float2 w3 = tw[3 * jm];
            float2 a0 = buf[cur][col][bq];
            float2 a1 = buf[cur][col][bq + 32];
            float2 a2 = buf[cur][col][bq + 64];
            float2 a3 = buf[cur][col][bq + 96];
            float2 s02 = cadd(a0, a2), d02 = csub(a0, a2);
            float2 s13 = cadd(a1, a3), d13 = csub(a1, a3);
            float2 b0 = cadd(s02, s13), b2 = csub(s02, s13);
            float2 b1 = make_float2(d02.x - (float)SIGN * d13.y,
                                    d02.y + (float)SIGN * d13.x);
            float2 b3 = make_float2(d02.x + (float)SIGN * d13.y,
                                    d02.y - (float)SIGN * d13.x);
            const int o = 4 * jm + k;
            buf[cur ^ 1][col][o] = b0;
            buf[cur ^ 1][col][o + m] = cmul(w1, b1);
            buf[cur ^ 1][col][o + 2 * m] = cmul(w2, b2);
            buf[cur ^ 1][col][o + 3 * m] = cmul(w3, b3);
        }
        cur ^= 1;
        m <<= 2;
    }
#pragma unroll
    for (int b = 0; b < 4; ++b) {  // radix-2 tail, m=64, j=0
        const int bt = r + 16 * b;
        float2 a = buf[cur][col][bt];
        float2 bb = buf[cur][col][bt + 64];
        buf[cur ^ 1][col][bt] = cadd(a, bb);
        buf[cur ^ 1][col][bt + 64] = csub(a, bb);
    }
    return cur ^ 1;
}

// K1: row FFT of x (N=128) with pack-2; write only cols 0..64 (Hermitian).
__global__ __launch_bounds__(256) void k1_fft_rows_x(const float* __restrict__ x,
                                                     float2* __restrict__ Fx) {
    __shared__ float2 buf[2][4][128];
    __shared__ float2 tw64m[64];
    const int tid = threadIdx.x;
    const int row = tid >> 6;   // pair slot 0..3
    const int t = tid & 63;
    fill_tw<64, -1, 256>(tw64m);
    const int gpair = blockIdx.x * 4 + row;  // img*64 + pr
    const float* r0 = x + (size_t)gpair * 256;        // row 2*pr (128 floats)
    const float* r1 = r0 + 128;                       // row 2*pr+1
    const float2 a0 = ((const float2*)r0)[t];
    const float2 a1 = ((const float2*)r1)[t];
    buf[0][row][2 * t].x = a0.x;
    buf[0][row][2 * t].y = a1.x;
    buf[0][row][2 * t + 1].x = a0.y;
    buf[0][row][2 * t + 1].y = a1.y;
    int cur = fft_lds_rows<128, 4, -1>(buf, tw64m);
    float2* d0 = Fx + (size_t)gpair * 256;            // Fx row 2*pr
    float2* d1 = d0 + 128;
    for (int h = 0; h < 2; ++h) {
        int tt = t + h * 64;
        if (tt > 64) continue;  // Hermitian: cols 65..127 reconstructed in k6
        float2 Zt = buf[cur][row][tt];
        float2 Zm = buf[cur][row][(128 - tt) & 127];
        d0[tt] = make_float2(0.5f * (Zt.x + Zm.x), 0.5f * (Zt.y - Zm.y));
        float ax = Zt.x - Zm.x, ay = Zt.y + Zm.y;
        d1[tt] = make_float2(0.5f * ay, -0.5f * ax);
    }
}

// K2: column FFT of Fx, in place, cols 0..64 only -> 5 tiles of 16.
__global__ __launch_bounds__(256) void k2_fft_cols_x(float2* __restrict__ Fx) {
    __shared__ float2 buf[2][16][130];
    __shared__ float2 tw[96];
    const int tid = threadIdx.x;
    const int img = blockIdx.x / 5;
    const int c0 = (blockIdx.x % 5) * 16;
    for (int i = tid; i < 96; i += 256) {
        float s, c;
        __sincosf(-(float)M_PI * (float)i / 64.f, &s, &c);
        tw[i] = make_float2(c, s);
    }
    float2* base = Fx + (size_t)img * 16384 + c0;
    for (int it = 0; it < 8; ++it) {
        int idx = it * 256 + tid;
        int rr = idx >> 4, cc = idx & 15;
        buf[0][cc][rr] = base[rr * 128 + cc];
    }
    __syncthreads();
    int cur = fft4_cols_wavelocal<-1, 16>(buf, tw);
    __syncthreads();
    for (int it = 0; it < 8; ++it) {
        int idx = it * 256 + tid;
        int rr = idx >> 4, cc = idx & 15;
        base[rr * 128 + cc] = buf[cur][cc][rr];
    }
}

// K3: row FFT of padded+rolled psf (N=256), compact output [img][25][256].
__global__ __launch_bounds__(128) void k3_fft_rows_k(const float* __restrict__ kin,
                                                     float2* __restrict__ FBtmp) {
    __shared__ float2 buf[2][1][256];
    __shared__ float2 tw128m[128];
    const int tid = threadIdx.x;  // 128
    const int img = blockIdx.x / 25;
    const int lr = blockIdx.x % 25;
    fill_tw<128, -1, 128>(tw128m);
    const float* krow = kin + img * 625 + lr * 25;
    for (int h = 0; h < 2; ++h) {
        int v = tid + h * 128;
        int pc = (v + 12) & 255;
        buf[0][0][v] = make_float2(pc < 25 ? krow[pc] : 0.f, 0.f);
    }
    int cur = fft_lds_rows<256, 1, -1>(buf, tw128m);
    float2* dst = FBtmp + (size_t)img * 6400 + lr * 256;
    dst[tid] = buf[cur][0][tid];
    dst[tid + 128] = buf[cur][0][tid + 128];
}

// K6: fused column-DFT (4 FBh rows from FBtmp) + M + FX build + radix-4 row
// IFFT + Hermitian column fold. Block = (img, p-pair {pa=2b, pb=2b+1}).
__global__ __launch_bounds__(256) void k6_fused(const float2* __restrict__ FBtmp,
                                                const float2* __restrict__ Fx,
                                                const float* __restrict__ alpha,
                                                float2* __restrict__ Zf) {
    __shared__ float2 stage[4][256];     // FBh rows pa,128-pa,pb,128-pb
    __shared__ float2 buf[2][4][288];    // padded: PHI(i)=i+(i>>3)
    __shared__ float2 tw[192];           // e^{+i pi k/128}, k<192
    __shared__ float2 Tt[2][25];         // DFT twiddles for u=pa (0) / u=pb (1)
    const int tid = threadIdx.x;
    const int rs = tid >> 6;             // row slot = wave id
    const int q = tid & 63;
    const int img = blockIdx.x / 33;
    const int bq = blockIdx.x % 33;
    const int pa = 2 * bq;
    const int pb = (pa + 1 < 65) ? (pa + 1) : 64;   // last block: pb==pa==64

    // Issue S loads early (coalesced over j=tid; FBtmp slab is L2-resident).
    const float2* src = FBtmp + (size_t)img * 6400 + tid;
    float2 S[25];
#pragma unroll
    for (int p = 0; p < 25; ++p) S[p] = src[p * 256];

    for (int i = tid; i < 192; i += 256) {
        float s, c;
        __sincosf((float)M_PI * (float)i / 128.f, &s, &c);
        tw[i] = make_float2(c, s);
    }
    {  // DFT twiddles: T_u[p] = W_256^{u(p+244)}, W = e^{-2pi i/256}
        const float k2pi = -2.f * (float)M_PI / 256.f;
        for (int i = tid; i < 50; i += 256) {
            const int which = i / 25, p = i - which * 25;
            const int u = which ? pb : pa;
            float s, c;
            __sincosf(k2pi * (float)((u * (p + 244)) & 255), &s, &c);
            Tt[which][p] = make_float2(c, s);
        }
    }
    __syncthreads();  // BARRIER 0: Tt visible

    // On-the-fly column DFT: 4 rows. Mirror row 128-u via
    //   FBh[128-u][j] = sum_p (-1)^p S[p] conj(T_u[p])  (same 4 products).
    {
        float2 aA = make_float2(0.f, 0.f), bA = make_float2(0.f, 0.f);
        float2 aB = make_float2(0.f, 0.f), bB = make_float2(0.f, 0.f);
#pragma unroll
        for (int p = 0; p < 25; ++p) {
            const float2 s = S[p];
            const float2 ta = Tt[0][p];
            const float axx = ta.x * s.x, ayy = ta.y * s.y;
            const float axy = ta.x * s.y, ayx = ta.y * s.x;
            aA.x += axx - ayy;
            aA.y += axy + ayx;
            if (p & 1) {
                bA.x -= axx + ayy;
                bA.y -= axy - ayx;
            } else {
                bA.x += axx + ayy;
                bA.y += axy - ayx;
            }
            const float2 tb = Tt[1][p];
            const float bxx = tb.x * s.x, byy = tb.y * s.y;
            const float bxy = tb.x * s.y, byx = tb.y * s.x;
            aB.x += bxx - byy;
            aB.y += bxy + byx;
            if (p & 1) {
                bB.x -= bxx + byy;
                bB.y -= bxy - byx;
            } else {
                bB.x += bxx + byy;
                bB.y += bxy - byx;
            }
        }
        stage[0][tid] = aA;   // FBh[pa]
        stage[1][tid] = bA;   // FBh[128-pa]
        stage[2][tid] = aB;   // FBh[pb]
        stage[3][tid] = bB;   // FBh[128-pb]
    }
    __syncthreads();  // BARRIER 1: stage[] + tw[] visible to all waves

    const int p = (rs < 2) ? pa : pb;
    const int sb = rs & 2;
    const int u = ((rs & 1) == 0) ? p : (128 - p);   // 0..128
    const int um = u & 127;
    const int msel = (um == p) ? 0 : 1;
    const int mi = sb | msel;
    const int oi = sb | (1 - msel);

    const float ci = tw[um].x, si = -tw[um].y;
    const float b = 1.f / (1.f + __expf(9.f - alpha[img & 63])) + 1e-3f;
    const float scale = 1.f / 65536.f;
    const float2 Di0 = make_float2(1.f + ci, si);
    const float2 Di1 = make_float2(1.f - ci, -si);
    const float2 Du = (u < 128) ? Di0 : Di1;
#pragma unroll
    for (int h = 0; h < 2; ++h) {
        const int t = q + 64 * h;        // 0..127
        float2 f00 = stage[mi][t];
        float2 f01 = stage[mi][t + 128];
        float2 f10, f11;
        if (um == 0) {  // rows {0,128}: row 128 direct
            f10 = stage[oi][t];
            f11 = stage[oi][t + 128];
        } else {
            f10 = conjf2(stage[oi][(256 - t) & 255]);
            f11 = conjf2(stage[oi][128 - t]);
        }
        // Fx stored cols 0..64 only; mirror t>64: conj(Fx[(128-um)%128][128-t])
        const bool mir = (t > 64);
        const int rr = mir ? ((128 - um) & 127) : um;
        const int cc = mir ? (128 - t) : t;
        float2 fx = Fx[(size_t)img * 16384 + rr * 128 + cc];
        if (mir) fx.y = -fx.y;
        const float cj = tw[t].x, sj = -tw[t].y;
        float2 Dj0 = make_float2(1.f + cj, sj);
        float2 Dj1 = make_float2(1.f - cj, -sj);
        // S1 = (f00*Dj0 + f01*Dj1)*Di0 + (f10*Dj0 + f11*Dj1)*Di1  (6 cmuls)
        float2 A = cadd(cmul(f00, Dj0), cmul(f01, Dj1));
        float2 Bt = cadd(cmul(f10, Dj0), cmul(f11, Dj1));
        float2 S1 = cadd(cmul(A, Di0), cmul(Bt, Di1));
        S1.x *= 0.25f;
        S1.y *= 0.25f;
        float S2 = 0.25f * (f00.x * f00.x + f00.y * f00.y + f01.x * f01.x + f01.y * f01.y +
                            f10.x * f10.x + f10.y * f10.y + f11.x * f11.x + f11.y * f11.y);
        float inv = 1.f / (S2 + b);
        float2 mm = make_float2((1.f - S1.x) * inv, (-S1.y) * inv);
        float2 c0v = (u < 128) ? f00 : f10;
        float2 c1v = (u < 128) ? f01 : f11;
        float2 t0 = cadd(cmul(conjf2(c0v), mm), cmul(Du, Dj0));
        float2 t1 = cadd(cmul(conjf2(c1v), mm), cmul(Du, Dj1));
        float2 FX0 = cmul(fx, t0);
        float2 FX1 = cmul(fx, t1);
        buf[0][rs][PHI(t)] = make_float2(FX0.x * scale, FX0.y * scale);
        buf[0][rs][PHI(t + 128)] = make_float2(FX1.x * scale, FX1.y * scale);
    }

    // radix-4 Stockham IFFT (sigma=+1), wave-local: no barriers.
    int cur = 0, m = 1;
#pragma unroll
    for (int st = 0; st < 4; ++st) {
        const int k = q & (m - 1);
        const int jm = q - k;
        const float2 w1 = tw[jm];
        const float2 w2 = tw[2 * jm];
        const float2 w3 = tw[3 * jm];
        float2 a0 = buf[cur][rs][PHI(q)];
        float2 a1 = buf[cur][rs][PHI(q + 64)];
        float2 a2 = buf[cur][rs][PHI(q + 128)];
        float2 a3 = buf[cur][rs][PHI(q + 192)];
        float2 s02 = cadd(a0, a2), d02 = csub(a0, a2);
        float2 s13 = cadd(a1, a3), d13 = csub(a1, a3);
        float2 b0 = cadd(s02, s13), b2v = csub(s02, s13);
        float2 b1 = make_float2(d02.x - d13.y, d02.y + d13.x);   // d02 + i*d13
        float2 b3 = make_float2(d02.x + d13.y, d02.y - d13.x);   // d02 - i*d13
        const int o = 4 * jm + k;
        buf[cur ^ 1][rs][PHI(o)] = b0;
        buf[cur ^ 1][rs][PHI(o + m)] = cmul(w1, b1);
        buf[cur ^ 1][rs][PHI(o + 2 * m)] = cmul(w2, b2v);
        buf[cur ^ 1][rs][PHI(o + 3 * m)] = cmul(w3, b3);
        cur ^= 1;
        m <<= 2;
    }
    __syncthreads();  // BARRIER 2: cross-wave fold reads rs^1

    // Hermitian fold: Zf[u0] = (Z[u0]+conj(Z[128-u0])) + i*w.(Z[u0]-conj(Z[128-u0]))
    const int u0 = u;
    bool dowrite = ((rs & 1) == 0) ? true : (p > 0 && p < 64);
    if (pb == pa && rs >= 2) dowrite = false;  // last-block dedup
    if (dowrite) {
        const float2 w = tw[u0];
        float2* zb = Zf + (size_t)img * 32768 + (size_t)u0 * 256;
#pragma unroll
        for (int hh = 0; hh < 4; ++hh) {
            const int jj = q + 64 * hh;
            float2 su = buf[cur][rs][PHI(jj)];
            float2 s2 = buf[cur][rs ^ 1][PHI(jj)];
            float2 e = make_float2(su.x + s2.x, su.y - s2.y);   // su + conj(s2)
            float2 o_ = make_float2(su.x - s2.x, su.y + s2.y);  // su - conj(s2)
            float2 wo = cmul(w, o_);
            zb[jj] = make_float2(e.x - wo.y, e.y + wo.x);       // e + i*wo
        }
    }
}

// K7: pure C2R column IFFT (wave-local radix-4), 16 cols/block.
__global__ __launch_bounds__(256) void k7_c2r(const float2* __restrict__ Zf,
                                              float* __restrict__ out) {
    __shared__ float2 buf[2][16][130];
    __shared__ float2 tw[96];  // e^{+i pi k/64}
    const int tid = threadIdx.x;
    const int img = blockIdx.x >> 4;
    const int c0 = (blockIdx.x & 15) * 16;
    for (int i = tid; i < 96; i += 256) {
        float s, c;
        __sincosf((float)M_PI * (float)i / 64.f, &s, &c);
        tw[i] = make_float2(c, s);
    }
    const float2* zb = Zf + (size_t)img * 32768 + c0;
    for (int it = 0; it < 8; ++it) {
        int idx = it * 256 + tid;
        int rr = idx >> 4, cc = idx & 15;
        buf[0][cc][rr] = zb[rr * 256 + cc];
    }
    __syncthreads();
    int cur = fft4_cols_wavelocal<1, 16>(buf, tw);
    __syncthreads();
    float* ob = out + (size_t)img * 65536 + c0;
    for (int it = 0; it < 8; ++it) {
        int idx = it * 256 + tid;
        int n = idx >> 4, c = idx & 15;
        float2 y = buf[cur][c][n];
        ob[(2 * n) * 256 + c] = y.x;
        ob[(2 * n + 1) * 256 + c] = y.y;
    }
}

extern "C" void kernel_launch(void* const* d_in, const int* in_sizes, int n_in,
                              void* d_out, int out_size, void* d_ws, size_t ws_size,
                              hipStream_t stream) {
    const float* x = (const float*)d_in[0];      // (4,64,128,128)
    const float* k = (const float*)d_in[1];      // (4,64,25,25)
    const float* alpha = (const float*)d_in[2];  // (1,64,1,1)
    float* out = (float*)d_out;                  // (4,64,256,256)

    float2* Fx = (float2*)d_ws;           // 256*16384   = 32 MB (cols 0..64 live)
    float2* Zf = Fx + 256 * 16384;        // 256*128*256 = 64 MB (folded)
    float2* FBtmp = Zf + 256 * 32768;     // 256*25*256  = 13.1 MB

    hipLaunchKernelGGL(k1_fft_rows_x, dim3(4096), dim3(256), 0, stream, x, Fx);
    hipLaunchKernelGGL(k2_fft_cols_x, dim3(256 * 5), dim3(256), 0, stream, Fx);
    hipLaunchKernelGGL(k3_fft_rows_k, dim3(6400), dim3(128), 0, stream, k, FBtmp);
    hipLaunchKernelGGL(k6_fused, dim3(256 * 33), dim3(256), 0, stream, FBtmp, Fx, alpha, Zf);
    hipLaunchKernelGGL(k7_c2r, dim3(4096), dim3(256), 0, stream, Zf, out);
}